// Round 3
// baseline (585.949 us; speedup 1.0000x reference)
//
#include <hip/hip_runtime.h>
#include <math.h>

// Problem dims
#define B_ 4
#define L_ 512
#define MROWS 2048
#define D_MODEL 384
#define N_LAYER 4
#define D_INNER 768
#define N_STATE 16
#define DT_RANK 24
#define D_CONV 4
#define VOCAB 1544
#define FEAT 1536
#define XPROJ_N 56
#define NCH 8               // scan chunks per batch (L/64)
#define SCH 64              // scan chunk length
#define DG 4                // d-channels per scan block

typedef __attribute__((ext_vector_type(8))) short short8;
typedef __attribute__((ext_vector_type(4))) float floatx4;
typedef __attribute__((ext_vector_type(4))) _Float16 half4;

__device__ __forceinline__ float softplus_f(float x) { return x > 20.f ? x : log1pf(expf(x)); }
__device__ __forceinline__ float silu_f(float x) { return x / (1.f + __expf(-x)); }

// f32 -> bf16 (RNE), two packed into one u32
__device__ __forceinline__ unsigned pack2bf(float x, float y) {
    unsigned ux = __float_as_uint(x); ux = (ux + 0x7FFFu + ((ux >> 16) & 1u)) >> 16;
    unsigned uy = __float_as_uint(y); uy = (uy + 0x7FFFu + ((uy >> 16) & 1u)) >> 16;
    return ux | (uy << 16);
}

// DPP row-rotate add: x + (x ror N within each 16-lane row). After ror
// 8,4,2,1 every lane holds the full 16-sum.
template <int CTRL>
__device__ __forceinline__ float dpp_radd(float x) {
    int r = __builtin_amdgcn_update_dpp(0, __float_as_int(x), CTRL, 0xf, 0xf, true);
    return x + __int_as_float(r);
}

// Wave-local LDS fence: producer and consumer are the SAME wave (cross-lane
// ok) -- s_waitcnt makes the wave's own ds_writes visible, wave_barrier pins
// ordering. Replaces __syncthreads where no cross-wave data flows.
__device__ __forceinline__ void wave_lds_fence() {
    asm volatile("s_waitcnt lgkmcnt(0)" ::: "memory");
    __builtin_amdgcn_wave_barrier();
}

__device__ __forceinline__ float4 ld4_guard(const float* __restrict__ p, int k, int ke) {
    if (k + 3 < ke) return *(const float4*)(p + k);
    float4 r = make_float4(0.f, 0.f, 0.f, 0.f);
    if (k + 0 < ke) r.x = p[k + 0];
    if (k + 1 < ke) r.y = p[k + 1];
    if (k + 2 < ke) r.z = p[k + 2];
    return r;
}

__device__ __forceinline__ short8 ld8h_guard(const short* __restrict__ p, int k, int ke) {
    if (k + 7 < ke) return *(const short8*)(p + k);
    short8 r = {0, 0, 0, 0, 0, 0, 0, 0};
#pragma unroll
    for (int j = 0; j < 8; ++j)
        if (k + j < ke) r[j] = p[k + j];
    return r;
}

// ---------------------------------------------------------------------------
// One-shot weight/input cast f32 -> bf16 + grid-stride zeroing of atomic dsts.
// ---------------------------------------------------------------------------
struct CastDesc {
    const float* src[6];
    short*       dst[6];
    unsigned     cum[6];   // exclusive prefix ends, in float4 units
};

__global__ __launch_bounds__(256) void cast_w_k(CastDesc cd, unsigned total4,
                                                float4* __restrict__ zb, unsigned z4)
{
    unsigned i = blockIdx.x * 256 + threadIdx.x;
    if (i < total4) {
        int s = 0;
#pragma unroll
        for (int j = 0; j < 5; ++j)
            if (i >= cd.cum[j] && s == j) s = j + 1;
        unsigned off = i - (s ? cd.cum[s - 1] : 0u);
        float4 v = ((const float4*)cd.src[s])[off];
        uint2 pk;
        pk.x = pack2bf(v.x, v.y);
        pk.y = pack2bf(v.z, v.w);
        ((uint2*)cd.dst[s])[off] = pk;
    } else {
        unsigned zi = i - total4;
        if (zi < z4) zb[zi] = make_float4(0.f, 0.f, 0.f, 0.f);
    }
}

// ---------------------------------------------------------------------------
// MFMA bf16 GEMM: C[m,n] (+)= sum_k A[m,k]*W[n,k].  W pre-cast bf16.
// Pipelined K-loop: stage(k+1) -> prefetch(k+2) -> MFMA(k) -> barrier.
// ABF: A pre-cast bf16. EPI: 0 none, 1 +bias(z==0 if ATOMIC), 2 softplus+bias.
// ---------------------------------------------------------------------------
#define ASTR 40

template <int EPI, bool GATED, bool ATOMIC, bool RMSN, bool NG, bool ABF>
__global__ __launch_bounds__(256) void mfma_gemm(
    const float* __restrict__ A, const short* __restrict__ Abf,
    const short* __restrict__ Wb,
    const float* __restrict__ bias, const float* __restrict__ gate,
    const float* __restrict__ nw,
    float* __restrict__ C, int M, int N, int K, int lda, int ldg, int ldc, int KC)
{
    __shared__ short As[2][64 * ASTR];
    __shared__ short Ws[2][64 * ASTR];
    __shared__ float sscale[64];

    const int t  = threadIdx.x;
    const int m0 = blockIdx.y * 64;
    const int n0 = blockIdx.x * 64;
    const int ks = blockIdx.z * KC;
    const int ke = min(K, ks + KC);

    const int srow = t >> 2;           // 0..63
    const int sseg = (t & 3) * 8;      // 0,8,16,24

    if (RMSN) {
        const int row = t >> 2, q = t & 3;
        const float* xr = A + (size_t)(m0 + row) * lda + q * (K >> 2);
        float s = 0.f;
        for (int i = 0; i < (K >> 2); i += 4) {
            float4 v = *(const float4*)(xr + i);
            s += v.x * v.x + v.y * v.y + v.z * v.z + v.w * v.w;
        }
        s += __shfl_xor(s, 1, 64);
        s += __shfl_xor(s, 2, 64);
        if (q == 0) sscale[row] = rsqrtf(s / (float)K + 1e-5f);
        __syncthreads();
    }

    float4 ra0, ra1, rg0, rg1, rn0, rn1;
    short8 ra8, rw8;

    auto prefetch = [&](int k0) {
        if (ABF) {
            ra8 = ld8h_guard(Abf + (size_t)(m0 + srow) * lda, k0 + sseg, ke);
        } else {
            const float* ar = A + (size_t)(m0 + srow) * lda;
            ra0 = ld4_guard(ar, k0 + sseg, ke);
            ra1 = ld4_guard(ar, k0 + sseg + 4, ke);
            if (GATED) {
                const float* gr = gate + (size_t)(m0 + srow) * ldg;
                rg0 = ld4_guard(gr, k0 + sseg, ke);
                rg1 = ld4_guard(gr, k0 + sseg + 4, ke);
            }
            if (RMSN) {
                rn0 = ld4_guard(nw, k0 + sseg, ke);
                rn1 = ld4_guard(nw, k0 + sseg + 4, ke);
            }
        }
        if (!NG || (n0 + srow) < N) {
            rw8 = ld8h_guard(Wb + (size_t)(n0 + srow) * (size_t)K, k0 + sseg, ke);
        } else {
            rw8 = (short8){0, 0, 0, 0, 0, 0, 0, 0};
        }
    };

    auto stage = [&](int p) {
        if (ABF) {
            *(short8*)&As[p][srow * ASTR + sseg] = ra8;
        } else {
            float4 a0 = ra0, a1 = ra1;
            if (GATED) {
                a0.x *= silu_f(rg0.x); a0.y *= silu_f(rg0.y); a0.z *= silu_f(rg0.z); a0.w *= silu_f(rg0.w);
                a1.x *= silu_f(rg1.x); a1.y *= silu_f(rg1.y); a1.z *= silu_f(rg1.z); a1.w *= silu_f(rg1.w);
            }
            if (RMSN) {
                float sc = sscale[srow];
                a0.x *= sc * rn0.x; a0.y *= sc * rn0.y; a0.z *= sc * rn0.z; a0.w *= sc * rn0.w;
                a1.x *= sc * rn1.x; a1.y *= sc * rn1.y; a1.z *= sc * rn1.z; a1.w *= sc * rn1.w;
            }
            int4 pa;
            pa.x = pack2bf(a0.x, a0.y); pa.y = pack2bf(a0.z, a0.w);
            pa.z = pack2bf(a1.x, a1.y); pa.w = pack2bf(a1.z, a1.w);
            *(int4*)&As[p][srow * ASTR + sseg] = pa;
        }
        *(short8*)&Ws[p][srow * ASTR + sseg] = rw8;
    };

    prefetch(ks);
    stage(0);
    if (ks + 32 < ke) prefetch(ks + 32);   // loads for iter 2 in flight across barrier
    __syncthreads();

    floatx4 acc[2][2];
#pragma unroll
    for (int i = 0; i < 2; ++i)
#pragma unroll
        for (int j = 0; j < 2; ++j) acc[i][j] = (floatx4){0.f, 0.f, 0.f, 0.f};

    const int w    = t >> 6;
    const int lane = t & 63;
    const int quad = lane >> 4;
    const int lm   = lane & 15;
    const int aoff = ((w >> 1) * 32 + lm) * ASTR + quad * 8;
    const int boff = ((w & 1) * 32 + lm) * ASTR + quad * 8;

    int p = 0;
    for (int k0 = ks; k0 < ke; k0 += 32) {
        const bool more = (k0 + 32 < ke);
        if (more) {
            stage(p ^ 1);                       // consumes loads issued 1 iter ago
            if (k0 + 64 < ke) prefetch(k0 + 64); // issue 2 iters ahead
        }
        short8 a0 = *(const short8*)&As[p][aoff];
        short8 a1 = *(const short8*)&As[p][aoff + 16 * ASTR];
        short8 b0 = *(const short8*)&Ws[p][boff];
        short8 b1 = *(const short8*)&Ws[p][boff + 16 * ASTR];
        acc[0][0] = __builtin_amdgcn_mfma_f32_16x16x32_bf16(a0, b0, acc[0][0], 0, 0, 0);
        acc[0][1] = __builtin_amdgcn_mfma_f32_16x16x32_bf16(a0, b1, acc[0][1], 0, 0, 0);
        acc[1][0] = __builtin_amdgcn_mfma_f32_16x16x32_bf16(a1, b0, acc[1][0], 0, 0, 0);
        acc[1][1] = __builtin_amdgcn_mfma_f32_16x16x32_bf16(a1, b1, acc[1][1], 0, 0, 0);
        if (more) {
            __syncthreads();
            p ^= 1;
        }
    }

    const int rbase = m0 + (w >> 1) * 32 + quad * 4;
    const int cbase = n0 + (w & 1) * 32 + lm;
#pragma unroll
    for (int mt = 0; mt < 2; ++mt)
#pragma unroll
        for (int nt = 0; nt < 2; ++nt) {
            const int gc = cbase + nt * 16;
            if (NG && gc >= N) continue;
#pragma unroll
            for (int r = 0; r < 4; ++r) {
                const size_t gr = rbase + mt * 16 + r;
                float v = acc[mt][nt][r];
                if (ATOMIC) {
                    if (EPI == 1 && blockIdx.z == 0) v += bias[gc];
                    atomicAdd(&C[gr * ldc + gc], v);
                } else {
                    if (EPI == 1) v += bias[gc];
                    if (EPI == 2) v = softplus_f(v + bias[gc]);
                    C[gr * ldc + gc] = v;
                }
            }
        }
}

// ---------------------------------------------------------------------------
// Depthwise causal conv (width 4) + bias + SiLU; writes u (f32) and u_bf.
// ---------------------------------------------------------------------------
__global__ __launch_bounds__(256) void conv_silu_k(
    const float* __restrict__ xz, const float* __restrict__ w,
    const float* __restrict__ cb, float* __restrict__ u, short* __restrict__ ubf)
{
    int idx = blockIdx.x * 256 + threadIdx.x;
    if (idx >= MROWS * (D_INNER / 4)) return;
    int dq = idx % (D_INNER / 4);
    int m  = idx / (D_INNER / 4);
    int d0 = dq * 4;
    int b = m / L_, l = m % L_;
    float4 wq[4];
#pragma unroll
    for (int j = 0; j < 4; ++j) wq[j] = *(const float4*)(w + (d0 + j) * D_CONV);
    float acc[4];
#pragma unroll
    for (int j = 0; j < 4; ++j) acc[j] = cb[d0 + j];
#pragma unroll
    for (int tt = 0; tt < 4; ++tt) {
        int ll = l - 3 + tt;
        if (ll >= 0) {
            float4 xv = *(const float4*)(xz + (size_t)(b * L_ + ll) * (2 * D_INNER) + d0);
            acc[0] = fmaf(xv.x, ((const float*)&wq[0])[tt], acc[0]);
            acc[1] = fmaf(xv.y, ((const float*)&wq[1])[tt], acc[1]);
            acc[2] = fmaf(xv.z, ((const float*)&wq[2])[tt], acc[2]);
            acc[3] = fmaf(xv.w, ((const float*)&wq[3])[tt], acc[3]);
        }
    }
    float4 o = make_float4(silu_f(acc[0]), silu_f(acc[1]), silu_f(acc[2]), silu_f(acc[3]));
    *(float4*)(u + (size_t)m * D_INNER + d0) = o;
    uint2 pk;
    pk.x = pack2bf(o.x, o.y);
    pk.y = pack2bf(o.z, o.w);
    *(uint2*)(ubf + (size_t)m * D_INNER + d0) = pk;
}

// ---------------------------------------------------------------------------
// Fused selective scan (r2 restructure: LDS-resident inner loops).
//   phase 0 (per wave, own chunk c, no barrier):
//     - stage u rows (f32, coalesced float4)
//     - stage B|C slab (xdbl cols 24..55, ONE 128B span/row) as f16 -> 4KB/chunk
//     - delta = softplus(xdbl[:, :24] @ dtW.T + dtb) in f32 -> sd
//     - early-issue the phase-C xz gate load (consumed ~2000cy later)
//   phase A: local scan, ALL operands from LDS (r2: global scalar B/C loads
//     with 4-deep prefetch left ~300cy uncovered latency -> VALUBusy 50%).
//   __syncthreads (the ONLY block barrier: sP/sH cross-wave exchange)
//   phase B: carry-in fix for chunks 1..7, C from LDS.
//   phase C: gate with silu(res), emit bf16.
// LDS 60KB -> 2 blocks/CU.  Wave-private phases use wave_lds_fence only.
// ---------------------------------------------------------------------------
__global__ __launch_bounds__(512, 2) void scan_fused_k(
    const float* __restrict__ xdbl, const float* __restrict__ u,
    const float* __restrict__ xz,
    const float* __restrict__ dtW, const float* __restrict__ dtb,
    const float* __restrict__ A_log, const float* __restrict__ Dp,
    short* __restrict__ ybf)
{
    __shared__ __align__(16) float sd[NCH][SCH][DG];        // 8KB
    __shared__ __align__(16) float su[NCH][SCH][DG];        // 8KB
    __shared__ __align__(16) float sy[NCH][SCH][DG];        // 8KB
    __shared__ __align__(16) _Float16 sBC[NCH][SCH][32];    // 32KB  B|C f16
    __shared__ float sP[NCH][DG][16], sH[NCH][DG][16];      // 4KB

    const int t  = threadIdx.x;
    const int c  = t >> 6;          // chunk == wave
    const int dl = (t >> 4) & 3;
    const int n  = t & 15;
    const int lt = t & 63;
    // XCD-chunked swizzle (bijective, 192 = 8 * 24): adjacent d-groups share
    // cache lines of u/xz/ybf -> keep them on one XCD (r1: FETCH 51->8MB).
    const int bx  = blockIdx.x;
    const int dgi = (bx & 7) * (D_INNER / DG / 8) + (bx >> 3);
    const int d0 = dgi * DG;
    const int d  = d0 + dl;
    const int b  = blockIdx.y;
    const size_t rbase = (size_t)b * L_ + c * SCH;

    // ---- phase 0: wave-private staging ----
    // early-issue phase-C gate load (xz residual half)
    float4 rv = *(const float4*)(xz + (rbase + lt) * (2 * D_INNER) + D_INNER + d0);

    // u rows (f32)
    *(float4*)&su[c][lt][0] = *(const float4*)(u + (rbase + lt) * D_INNER + d0);

    // B|C slab -> f16 LDS (cols 24..55 of xdbl; contiguous 128B per row)
    {
        const float* xrow = xdbl + rbase * XPROJ_N + DT_RANK;
        const int srow = lt >> 3;      // 0..7
        const int slot = lt & 7;       // 0..7 float4 slots
#pragma unroll
        for (int rr = 0; rr < 8; ++rr) {
            const int row = rr * 8 + srow;
            float4 v = *(const float4*)(xrow + (size_t)row * XPROJ_N + slot * 4);
            half4 hv = {(_Float16)v.x, (_Float16)v.y, (_Float16)v.z, (_Float16)v.w};
            *(half4*)&sBC[c][row][slot * 4] = hv;
        }
    }

    // delta = softplus(dt-proj) in f32
    {
        float4 w4[6];
#pragma unroll
        for (int q = 0; q < 6; ++q) w4[q] = *(const float4*)(dtW + (size_t)d * DT_RANK + q * 4);
        const float bias = dtb[d];
#pragma unroll
        for (int k = 0; k < 4; ++k) {
            const float* xr = xdbl + (rbase + n * 4 + k) * XPROJ_N;
            float acc = bias;
#pragma unroll
            for (int q = 0; q < 6; ++q) {
                float4 xv = *(const float4*)(xr + q * 4);
                acc = fmaf(xv.x, ((const float*)&w4[q])[0], acc);
                acc = fmaf(xv.y, ((const float*)&w4[q])[1], acc);
                acc = fmaf(xv.z, ((const float*)&w4[q])[2], acc);
                acc = fmaf(xv.w, ((const float*)&w4[q])[3], acc);
            }
            sd[c][n * 4 + k][dl] = softplus_f(acc);
        }
    }
    wave_lds_fence();   // all phase-0 writes are wave-private to chunk c

    // ---- phase A: local scan over own chunk (LDS-only operands) ----
    const float Av = -expf(A_log[d * N_STATE + n]);
    const float Dd = Dp[d];

    float h = 0.f, pacc = 1.f;
#pragma unroll 4
    for (int j = 0; j < SCH; ++j) {
        float dv = sd[c][j][dl];
        float uv = su[c][j][dl];
        float Bv = (float)sBC[c][j][n];
        float Cv = (float)sBC[c][j][16 + n];
        float e  = __expf(dv * Av);
        h = fmaf(e, h, dv * uv * Bv);
        pacc *= e;
        float p = h * Cv;
        p = dpp_radd<0x128>(p);
        p = dpp_radd<0x124>(p);
        p = dpp_radd<0x122>(p);
        p = dpp_radd<0x121>(p);
        if (n == 0) sy[c][j][dl] = fmaf(uv, Dd, p);
    }
    sP[c][dl][n] = pacc;
    sH[c][dl][n] = h;
    __syncthreads();    // the only cross-wave exchange (sP/sH)

    // ---- phase B: carry-in correction for chunks 1..7 ----
    if (c > 0) {
        float hs = 0.f;
        for (int s = 0; s < c; ++s)
            hs = fmaf(sP[s][dl][n], hs, sH[s][dl][n]);
        float gv = hs;
#pragma unroll 4
        for (int j = 0; j < SCH; ++j) {
            float dv = sd[c][j][dl];
            float Cv = (float)sBC[c][j][16 + n];
            gv *= __expf(dv * Av);
            float p = gv * Cv;
            p = dpp_radd<0x128>(p);
            p = dpp_radd<0x124>(p);
            p = dpp_radd<0x122>(p);
            p = dpp_radd<0x121>(p);
            if (n == 0) sy[c][j][dl] += p;
        }
    }
    wave_lds_fence();   // sy[c] is wave-private

    // ---- phase C: gate with silu(res) and emit bf16 ----
    {
        const size_t row = rbase + lt;
        float4 yv = *(const float4*)&sy[c][lt][0];
        float o0 = yv.x * silu_f(rv.x);
        float o1 = yv.y * silu_f(rv.y);
        float o2 = yv.z * silu_f(rv.z);
        float o3 = yv.w * silu_f(rv.w);
        uint2 pk;
        pk.x = pack2bf(o0, o1);
        pk.y = pack2bf(o2, o3);
        *(uint2*)(ybf + row * D_INNER + d0) = pk;
    }
}

// ---------------------------------------------------------------------------
extern "C" void kernel_launch(void* const* d_in, const int* in_sizes, int n_in,
                              void* d_out, int out_size, void* d_ws, size_t ws_size,
                              hipStream_t stream)
{
    const float* input_ids = (const float*)d_in[0];
    const float* fc_W      = (const float*)d_in[1];
    const float* fc_b      = (const float*)d_in[2];
    const float* in_proj_W = (const float*)d_in[3];
    const float* conv_W    = (const float*)d_in[4];
    const float* conv_b    = (const float*)d_in[5];
    const float* x_proj_W  = (const float*)d_in[6];
    const float* dt_proj_W = (const float*)d_in[7];
    const float* dt_proj_b = (const float*)d_in[8];
    const float* A_log     = (const float*)d_in[9];
    const float* Dp        = (const float*)d_in[10];
    const float* out_proj_W= (const float*)d_in[11];
    const float* norm_W    = (const float*)d_in[12];
    const float* normf_W   = (const float*)d_in[13];
    const float* head_W    = (const float*)d_in[14];
    float* out = (float*)d_out;

    float* ws       = (float*)d_ws;
    // f32 region: x_ws + per-layer xdbl contiguous (single zero span), then xz, u.
    float* x_ws     = ws;                                        // M*384
    float* xdbl_ws  = x_ws    + (size_t)MROWS * D_MODEL;         // 4 * M*56
    float* xz_ws    = xdbl_ws + (size_t)N_LAYER * MROWS * XPROJ_N; // M*1536
    float* u_ws     = xz_ws   + (size_t)MROWS * 2 * D_INNER;     // M*768
    // bf16 region
    short* bf       = (short*)(u_ws + (size_t)MROWS * D_INNER);
    short* wbf_fc   = bf;
    short* wbf_in   = wbf_fc  + (size_t)D_MODEL * VOCAB;
    short* wbf_x    = wbf_in  + (size_t)N_LAYER * 2 * D_INNER * D_MODEL;
    short* wbf_out  = wbf_x   + (size_t)N_LAYER * XPROJ_N * D_INNER;
    short* wbf_head = wbf_out + (size_t)N_LAYER * D_MODEL * D_INNER;
    short* ids_bf   = wbf_head+ (size_t)FEAT * D_MODEL;
    short* ubf_ws   = ids_bf  + (size_t)MROWS * VOCAB;
    short* ybf_ws   = ubf_ws  + (size_t)MROWS * D_INNER;

    const dim3 blk(256);
    const dim3 blk512(512);

    // --- one-shot cast to bf16 (weights + input_ids) + zero atomic dst buffers ---
    CastDesc cd;
    cd.src[0] = fc_W;       cd.dst[0] = wbf_fc;
    cd.src[1] = in_proj_W;  cd.dst[1] = wbf_in;
    cd.src[2] = x_proj_W;   cd.dst[2] = wbf_x;
    cd.src[3] = out_proj_W; cd.dst[3] = wbf_out;
    cd.src[4] = head_W;     cd.dst[4] = wbf_head;
    cd.src[5] = input_ids;  cd.dst[5] = ids_bf;
    unsigned c0 = (unsigned)(D_MODEL * VOCAB / 4);
    unsigned c1 = c0 + (unsigned)(N_LAYER * 2 * D_INNER * D_MODEL / 4);
    unsigned c2 = c1 + (unsigned)(N_LAYER * XPROJ_N * D_INNER / 4);
    unsigned c3 = c2 + (unsigned)(N_LAYER * D_MODEL * D_INNER / 4);
    unsigned c4 = c3 + (unsigned)(FEAT * D_MODEL / 4);
    unsigned c5 = c4 + (unsigned)(MROWS * VOCAB / 4);
    cd.cum[0] = c0; cd.cum[1] = c1; cd.cum[2] = c2;
    cd.cum[3] = c3; cd.cum[4] = c4; cd.cum[5] = c5;
    const unsigned zero4 = (unsigned)((MROWS * D_MODEL + N_LAYER * MROWS * XPROJ_N) / 4);
    cast_w_k<<<(c5 + zero4 + 255) / 256, blk, 0, stream>>>(cd, c5, (float4*)x_ws, zero4);

    // x = input_ids @ fc_W.T + fc_b   (A pre-cast bf16, split-K=7, atomic)
    mfma_gemm<1, false, true, false, false, true><<<dim3(D_MODEL / 64, MROWS / 64, 7), blk, 0, stream>>>(
        nullptr, ids_bf, wbf_fc, fc_b, nullptr, nullptr, x_ws,
        MROWS, D_MODEL, VOCAB, VOCAB, 0, D_MODEL, 256);

    for (int i = 0; i < N_LAYER; ++i) {
        float* xdbl_i = xdbl_ws + (size_t)i * MROWS * XPROJ_N;

        // xz = rmsnorm(x, norm_W) @ in_proj_W.T   (rmsnorm fused into A staging)
        mfma_gemm<0, false, false, true, false, false><<<dim3(2 * D_INNER / 64, MROWS / 64, 1), blk, 0, stream>>>(
            x_ws, nullptr, wbf_in + (size_t)i * 2 * D_INNER * D_MODEL,
            nullptr, nullptr, norm_W + i * D_MODEL, xz_ws,
            MROWS, 2 * D_INNER, D_MODEL, D_MODEL, 0, 2 * D_INNER, D_MODEL);

        // u = silu(conv(xz[:, :768]) + conv_b)  (f32 + bf16 copies)
        conv_silu_k<<<(MROWS * (D_INNER / 4) + 255) / 256, blk, 0, stream>>>(
            xz_ws, conv_W + (size_t)i * D_INNER * D_CONV, conv_b + i * D_INNER,
            u_ws, ubf_ws);

        // x_dbl = u @ x_proj_W[i].T  (A pre-cast bf16, N=56 guarded, split-K=6,
        // dst pre-zeroed once in cast_w_k -- per-layer buffer)
        mfma_gemm<0, false, true, false, true, true><<<dim3(1, MROWS / 64, 6), blk, 0, stream>>>(
            nullptr, ubf_ws, wbf_x + (size_t)i * XPROJ_N * D_INNER,
            nullptr, nullptr, nullptr, xdbl_i,
            MROWS, XPROJ_N, D_INNER, D_INNER, 0, XPROJ_N, 128);

        // fused: dt_proj+softplus -> two-phase chunked scan -> gate -> ybf (bf16)
        scan_fused_k<<<dim3(D_INNER / DG, B_), blk512, 0, stream>>>(
            xdbl_i, u_ws, xz_ws,
            dt_proj_W + (size_t)i * D_INNER * DT_RANK, dt_proj_b + i * D_INNER,
            A_log + (size_t)i * D_INNER * N_STATE, Dp + i * D_INNER, ybf_ws);

        // x += ybf @ out_proj_W.T  (A pre-cast bf16 gated y, split-K=2, atomic residual)
        mfma_gemm<0, false, true, false, false, true><<<dim3(D_MODEL / 64, MROWS / 64, 2), blk, 0, stream>>>(
            nullptr, ybf_ws, wbf_out + (size_t)i * D_MODEL * D_INNER,
            nullptr, nullptr, nullptr, x_ws,
            MROWS, D_MODEL, D_INNER, D_INNER, 0, D_MODEL, 384);
    }

    // out = rmsnorm(x, normf_W) @ head_W.T  (rmsnorm fused)
    mfma_gemm<0, false, false, true, false, false><<<dim3(FEAT / 64, MROWS / 64, 1), blk, 0, stream>>>(
        x_ws, nullptr, wbf_head, nullptr, nullptr, normf_W, out,
        MROWS, FEAT, D_MODEL, D_MODEL, 0, FEAT, D_MODEL);
}

// Round 4
// 555.516 us; speedup vs baseline: 1.0548x; 1.0548x over previous
//
#include <hip/hip_runtime.h>
#include <math.h>

// Problem dims
#define B_ 4
#define L_ 512
#define MROWS 2048
#define D_MODEL 384
#define N_LAYER 4
#define D_INNER 768
#define N_STATE 16
#define DT_RANK 24
#define D_CONV 4
#define VOCAB 1544
#define FEAT 1536
#define XPROJ_N 56
#define NCH 16              // scan chunks per batch (L/32)
#define SCH 32              // scan chunk length
#define DG 2                // d-channels per scan block

typedef __attribute__((ext_vector_type(8))) short short8;
typedef __attribute__((ext_vector_type(4))) float floatx4;

__device__ __forceinline__ float softplus_f(float x) { return x > 20.f ? x : log1pf(expf(x)); }
__device__ __forceinline__ float silu_f(float x) { return x / (1.f + __expf(-x)); }

// f32 -> bf16 (RNE), two packed into one u32
__device__ __forceinline__ unsigned pack2bf(float x, float y) {
    unsigned ux = __float_as_uint(x); ux = (ux + 0x7FFFu + ((ux >> 16) & 1u)) >> 16;
    unsigned uy = __float_as_uint(y); uy = (uy + 0x7FFFu + ((uy >> 16) & 1u)) >> 16;
    return ux | (uy << 16);
}

// DPP row-rotate add: x + (x ror N within each 16-lane row). After ror
// 8,4,2,1 every lane holds the full 16-sum.
template <int CTRL>
__device__ __forceinline__ float dpp_radd(float x) {
    int r = __builtin_amdgcn_update_dpp(0, __float_as_int(x), CTRL, 0xf, 0xf, true);
    return x + __int_as_float(r);
}

// Wave-local LDS fence: producer and consumer are the SAME wave (cross-lane
// ok) -- s_waitcnt makes the wave's own ds_writes visible, wave_barrier pins
// ordering. Replaces __syncthreads where no cross-wave data flows.
__device__ __forceinline__ void wave_lds_fence() {
    asm volatile("s_waitcnt lgkmcnt(0)" ::: "memory");
    __builtin_amdgcn_wave_barrier();
}

__device__ __forceinline__ float4 ld4_guard(const float* __restrict__ p, int k, int ke) {
    if (k + 3 < ke) return *(const float4*)(p + k);
    float4 r = make_float4(0.f, 0.f, 0.f, 0.f);
    if (k + 0 < ke) r.x = p[k + 0];
    if (k + 1 < ke) r.y = p[k + 1];
    if (k + 2 < ke) r.z = p[k + 2];
    return r;
}

__device__ __forceinline__ short8 ld8h_guard(const short* __restrict__ p, int k, int ke) {
    if (k + 7 < ke) return *(const short8*)(p + k);
    short8 r = {0, 0, 0, 0, 0, 0, 0, 0};
#pragma unroll
    for (int j = 0; j < 8; ++j)
        if (k + j < ke) r[j] = p[k + j];
    return r;
}

// ---------------------------------------------------------------------------
// One-shot weight/input cast f32 -> bf16 + grid-stride zeroing of atomic dsts.
// ---------------------------------------------------------------------------
struct CastDesc {
    const float* src[6];
    short*       dst[6];
    unsigned     cum[6];   // exclusive prefix ends, in float4 units
};

__global__ __launch_bounds__(256) void cast_w_k(CastDesc cd, unsigned total4,
                                                float4* __restrict__ zb, unsigned z4)
{
    unsigned i = blockIdx.x * 256 + threadIdx.x;
    if (i < total4) {
        int s = 0;
#pragma unroll
        for (int j = 0; j < 5; ++j)
            if (i >= cd.cum[j] && s == j) s = j + 1;
        unsigned off = i - (s ? cd.cum[s - 1] : 0u);
        float4 v = ((const float4*)cd.src[s])[off];
        uint2 pk;
        pk.x = pack2bf(v.x, v.y);
        pk.y = pack2bf(v.z, v.w);
        ((uint2*)cd.dst[s])[off] = pk;
    } else {
        unsigned zi = i - total4;
        if (zi < z4) zb[zi] = make_float4(0.f, 0.f, 0.f, 0.f);
    }
}

// ---------------------------------------------------------------------------
// MFMA bf16 GEMM: C[m,n] (+)= sum_k A[m,k]*W[n,k].  W pre-cast bf16.
// Pipelined K-loop: stage(k+1) -> prefetch(k+2) -> MFMA(k) -> barrier.
// ABF: A pre-cast bf16. EPI: 0 none, 1 +bias(z==0 if ATOMIC), 2 softplus+bias.
// ---------------------------------------------------------------------------
#define ASTR 40

template <int EPI, bool GATED, bool ATOMIC, bool RMSN, bool NG, bool ABF>
__global__ __launch_bounds__(256) void mfma_gemm(
    const float* __restrict__ A, const short* __restrict__ Abf,
    const short* __restrict__ Wb,
    const float* __restrict__ bias, const float* __restrict__ gate,
    const float* __restrict__ nw,
    float* __restrict__ C, int M, int N, int K, int lda, int ldg, int ldc, int KC)
{
    __shared__ short As[2][64 * ASTR];
    __shared__ short Ws[2][64 * ASTR];
    __shared__ float sscale[64];

    const int t  = threadIdx.x;
    const int m0 = blockIdx.y * 64;
    const int n0 = blockIdx.x * 64;
    const int ks = blockIdx.z * KC;
    const int ke = min(K, ks + KC);

    const int srow = t >> 2;           // 0..63
    const int sseg = (t & 3) * 8;      // 0,8,16,24

    if (RMSN) {
        const int row = t >> 2, q = t & 3;
        const float* xr = A + (size_t)(m0 + row) * lda + q * (K >> 2);
        float s = 0.f;
        for (int i = 0; i < (K >> 2); i += 4) {
            float4 v = *(const float4*)(xr + i);
            s += v.x * v.x + v.y * v.y + v.z * v.z + v.w * v.w;
        }
        s += __shfl_xor(s, 1, 64);
        s += __shfl_xor(s, 2, 64);
        if (q == 0) sscale[row] = rsqrtf(s / (float)K + 1e-5f);
        __syncthreads();
    }

    float4 ra0, ra1, rg0, rg1, rn0, rn1;
    short8 ra8, rw8;

    auto prefetch = [&](int k0) {
        if (ABF) {
            ra8 = ld8h_guard(Abf + (size_t)(m0 + srow) * lda, k0 + sseg, ke);
        } else {
            const float* ar = A + (size_t)(m0 + srow) * lda;
            ra0 = ld4_guard(ar, k0 + sseg, ke);
            ra1 = ld4_guard(ar, k0 + sseg + 4, ke);
            if (GATED) {
                const float* gr = gate + (size_t)(m0 + srow) * ldg;
                rg0 = ld4_guard(gr, k0 + sseg, ke);
                rg1 = ld4_guard(gr, k0 + sseg + 4, ke);
            }
            if (RMSN) {
                rn0 = ld4_guard(nw, k0 + sseg, ke);
                rn1 = ld4_guard(nw, k0 + sseg + 4, ke);
            }
        }
        if (!NG || (n0 + srow) < N) {
            rw8 = ld8h_guard(Wb + (size_t)(n0 + srow) * (size_t)K, k0 + sseg, ke);
        } else {
            rw8 = (short8){0, 0, 0, 0, 0, 0, 0, 0};
        }
    };

    auto stage = [&](int p) {
        if (ABF) {
            *(short8*)&As[p][srow * ASTR + sseg] = ra8;
        } else {
            float4 a0 = ra0, a1 = ra1;
            if (GATED) {
                a0.x *= silu_f(rg0.x); a0.y *= silu_f(rg0.y); a0.z *= silu_f(rg0.z); a0.w *= silu_f(rg0.w);
                a1.x *= silu_f(rg1.x); a1.y *= silu_f(rg1.y); a1.z *= silu_f(rg1.z); a1.w *= silu_f(rg1.w);
            }
            if (RMSN) {
                float sc = sscale[srow];
                a0.x *= sc * rn0.x; a0.y *= sc * rn0.y; a0.z *= sc * rn0.z; a0.w *= sc * rn0.w;
                a1.x *= sc * rn1.x; a1.y *= sc * rn1.y; a1.z *= sc * rn1.z; a1.w *= sc * rn1.w;
            }
            int4 pa;
            pa.x = pack2bf(a0.x, a0.y); pa.y = pack2bf(a0.z, a0.w);
            pa.z = pack2bf(a1.x, a1.y); pa.w = pack2bf(a1.z, a1.w);
            *(int4*)&As[p][srow * ASTR + sseg] = pa;
        }
        *(short8*)&Ws[p][srow * ASTR + sseg] = rw8;
    };

    prefetch(ks);
    stage(0);
    if (ks + 32 < ke) prefetch(ks + 32);   // loads for iter 2 in flight across barrier
    __syncthreads();

    floatx4 acc[2][2];
#pragma unroll
    for (int i = 0; i < 2; ++i)
#pragma unroll
        for (int j = 0; j < 2; ++j) acc[i][j] = (floatx4){0.f, 0.f, 0.f, 0.f};

    const int w    = t >> 6;
    const int lane = t & 63;
    const int quad = lane >> 4;
    const int lm   = lane & 15;
    const int aoff = ((w >> 1) * 32 + lm) * ASTR + quad * 8;
    const int boff = ((w & 1) * 32 + lm) * ASTR + quad * 8;

    int p = 0;
    for (int k0 = ks; k0 < ke; k0 += 32) {
        const bool more = (k0 + 32 < ke);
        if (more) {
            stage(p ^ 1);                       // consumes loads issued 1 iter ago
            if (k0 + 64 < ke) prefetch(k0 + 64); // issue 2 iters ahead
        }
        short8 a0 = *(const short8*)&As[p][aoff];
        short8 a1 = *(const short8*)&As[p][aoff + 16 * ASTR];
        short8 b0 = *(const short8*)&Ws[p][boff];
        short8 b1 = *(const short8*)&Ws[p][boff + 16 * ASTR];
        acc[0][0] = __builtin_amdgcn_mfma_f32_16x16x32_bf16(a0, b0, acc[0][0], 0, 0, 0);
        acc[0][1] = __builtin_amdgcn_mfma_f32_16x16x32_bf16(a0, b1, acc[0][1], 0, 0, 0);
        acc[1][0] = __builtin_amdgcn_mfma_f32_16x16x32_bf16(a1, b0, acc[1][0], 0, 0, 0);
        acc[1][1] = __builtin_amdgcn_mfma_f32_16x16x32_bf16(a1, b1, acc[1][1], 0, 0, 0);
        if (more) {
            __syncthreads();
            p ^= 1;
        }
    }

    const int rbase = m0 + (w >> 1) * 32 + quad * 4;
    const int cbase = n0 + (w & 1) * 32 + lm;
#pragma unroll
    for (int mt = 0; mt < 2; ++mt)
#pragma unroll
        for (int nt = 0; nt < 2; ++nt) {
            const int gc = cbase + nt * 16;
            if (NG && gc >= N) continue;
#pragma unroll
            for (int r = 0; r < 4; ++r) {
                const size_t gr = rbase + mt * 16 + r;
                float v = acc[mt][nt][r];
                if (ATOMIC) {
                    if (EPI == 1 && blockIdx.z == 0) v += bias[gc];
                    atomicAdd(&C[gr * ldc + gc], v);
                } else {
                    if (EPI == 1) v += bias[gc];
                    if (EPI == 2) v = softplus_f(v + bias[gc]);
                    C[gr * ldc + gc] = v;
                }
            }
        }
}

// ---------------------------------------------------------------------------
// Depthwise causal conv (width 4) + bias + SiLU; writes u (f32) and u_bf.
// ---------------------------------------------------------------------------
__global__ __launch_bounds__(256) void conv_silu_k(
    const float* __restrict__ xz, const float* __restrict__ w,
    const float* __restrict__ cb, float* __restrict__ u, short* __restrict__ ubf)
{
    int idx = blockIdx.x * 256 + threadIdx.x;
    if (idx >= MROWS * (D_INNER / 4)) return;
    int dq = idx % (D_INNER / 4);
    int m  = idx / (D_INNER / 4);
    int d0 = dq * 4;
    int b = m / L_, l = m % L_;
    float4 wq[4];
#pragma unroll
    for (int j = 0; j < 4; ++j) wq[j] = *(const float4*)(w + (d0 + j) * D_CONV);
    float acc[4];
#pragma unroll
    for (int j = 0; j < 4; ++j) acc[j] = cb[d0 + j];
#pragma unroll
    for (int tt = 0; tt < 4; ++tt) {
        int ll = l - 3 + tt;
        if (ll >= 0) {
            float4 xv = *(const float4*)(xz + (size_t)(b * L_ + ll) * (2 * D_INNER) + d0);
            acc[0] = fmaf(xv.x, ((const float*)&wq[0])[tt], acc[0]);
            acc[1] = fmaf(xv.y, ((const float*)&wq[1])[tt], acc[1]);
            acc[2] = fmaf(xv.z, ((const float*)&wq[2])[tt], acc[2]);
            acc[3] = fmaf(xv.w, ((const float*)&wq[3])[tt], acc[3]);
        }
    }
    float4 o = make_float4(silu_f(acc[0]), silu_f(acc[1]), silu_f(acc[2]), silu_f(acc[3]));
    *(float4*)(u + (size_t)m * D_INNER + d0) = o;
    uint2 pk;
    pk.x = pack2bf(o.x, o.y);
    pk.y = pack2bf(o.z, o.w);
    *(uint2*)(ubf + (size_t)m * D_INNER + d0) = pk;
}

// ---------------------------------------------------------------------------
// Fused selective scan, r4: NCH=16/SCH=32/DG=2 -- each wave owns TWO chunks
// (lane = ch*32 + dl*16 + n), halving the serial j-span per block vs r2
// (32+32 iters instead of 64+64).  LDS back to 16KB (r3's 60KB cut
// occupancy 50->32% and regressed).  B/C read from global with 8-deep
// register prefetch (r2's 4-deep left latency uncovered).  One block
// barrier only (sP/sH); all other LDS flows are wave-private.
//   phase 0: stage u (float2/row-task), delta = softplus(dt-dot) f32,
//            early-issue phase-C xz gate load
//   phase A: local scan, 32 j
//   phase B: carry fix, 32 j (only chunk-0 lanes idle = 1/32 waste)
//   phase C: gate + bf16 emit
// ---------------------------------------------------------------------------
__global__ __launch_bounds__(512, 4) void scan_fused_k(
    const float* __restrict__ xdbl, const float* __restrict__ u,
    const float* __restrict__ xz,
    const float* __restrict__ dtW, const float* __restrict__ dtb,
    const float* __restrict__ A_log, const float* __restrict__ Dp,
    short* __restrict__ ybf)
{
    __shared__ __align__(16) float sd[NCH][SCH][DG];        // 4KB
    __shared__ __align__(16) float su[NCH][SCH][DG];        // 4KB
    __shared__ __align__(16) float sy[NCH][SCH][DG];        // 4KB
    __shared__ float sP[NCH][DG][16], sH[NCH][DG][16];      // 4KB

    const int t  = threadIdx.x;
    const int w  = t >> 6;          // wave 0..7
    const int l  = t & 63;
    const int ch = l >> 5;          // 0..1 -> which of the wave's two chunks
    const int c  = w * 2 + ch;      // chunk 0..15
    const int dl = (l >> 4) & 1;    // channel within block
    const int n  = l & 15;          // state index
    // XCD-chunked swizzle (bijective, 384 = 8 * 48): adjacent d-groups share
    // cache lines of u/xz/ybf -> keep them on one XCD (r1: FETCH 51->8MB).
    const int bx  = blockIdx.x;
    const int dgi = (bx & 7) * (D_INNER / DG / 8) + (bx >> 3);
    const int d0 = dgi * DG;
    const int d  = d0 + dl;
    const int b  = blockIdx.y;

    // row-task mapping (each thread owns one global row for staging/phase C)
    const int tc = t >> 5, tj = t & 31;          // tc in {2w, 2w+1} -> wave-private
    const size_t trow = (size_t)b * L_ + t;

    // ---- phase 0: wave-private staging ----
    // early-issue phase-C gate load (consumed ~2000cy later)
    float2 rv  = *(const float2*)(xz + trow * (2 * D_INNER) + D_INNER + d0);
    float2 uv2 = *(const float2*)(u + trow * D_INNER + d0);
    *(float2*)&su[tc][tj][0] = uv2;

    // delta = softplus(xdbl[:, :24] @ dtW.T + dtb) in f32; each lane does
    // rows {2n, 2n+1} of its chunk c for channel d.
    {
        float4 w4[6];
#pragma unroll
        for (int q = 0; q < 6; ++q) w4[q] = *(const float4*)(dtW + (size_t)d * DT_RANK + q * 4);
        const float bias = dtb[d];
#pragma unroll
        for (int rr = 0; rr < 2; ++rr) {
            const int j = n * 2 + rr;
            const float* xr = xdbl + ((size_t)b * L_ + c * SCH + j) * XPROJ_N;
            float acc = bias;
#pragma unroll
            for (int q = 0; q < 6; ++q) {
                float4 xv = *(const float4*)(xr + q * 4);
                acc = fmaf(xv.x, w4[q].x, acc);
                acc = fmaf(xv.y, w4[q].y, acc);
                acc = fmaf(xv.z, w4[q].z, acc);
                acc = fmaf(xv.w, w4[q].w, acc);
            }
            sd[c][j][dl] = softplus_f(acc);
        }
    }
    wave_lds_fence();   // sd/su for chunks {2w,2w+1} produced+consumed by wave w

    // ---- phase A: local scan over own chunk (32 j) ----
    const float Av = -expf(A_log[d * N_STATE + n]);
    const float Dd = Dp[d];
    const float* xbn = xdbl + ((size_t)b * L_ + c * SCH) * XPROJ_N + DT_RANK + n;

    float h = 0.f, pacc = 1.f;
    float rB[8], rC[8];
#pragma unroll
    for (int q = 0; q < 8; ++q) {
        rB[q] = xbn[q * XPROJ_N];
        rC[q] = xbn[q * XPROJ_N + N_STATE];
    }
#pragma unroll
    for (int g = 0; g < SCH / 8; ++g) {
        float nB[8], nC[8];
        if (g + 1 < SCH / 8) {
#pragma unroll
            for (int q = 0; q < 8; ++q) {
                nB[q] = xbn[(g * 8 + 8 + q) * XPROJ_N];
                nC[q] = xbn[(g * 8 + 8 + q) * XPROJ_N + N_STATE];
            }
        }
#pragma unroll
        for (int q = 0; q < 8; ++q) {
            const int j = g * 8 + q;
            float dv = sd[c][j][dl];
            float uv = su[c][j][dl];
            float e  = __expf(dv * Av);
            h = fmaf(e, h, dv * uv * rB[q]);
            pacc *= e;
            float p = h * rC[q];
            p = dpp_radd<0x128>(p);
            p = dpp_radd<0x124>(p);
            p = dpp_radd<0x122>(p);
            p = dpp_radd<0x121>(p);
            if (n == 0) sy[c][j][dl] = fmaf(uv, Dd, p);
        }
#pragma unroll
        for (int q = 0; q < 8; ++q) { rB[q] = nB[q]; rC[q] = nC[q]; }
    }
    sP[c][dl][n] = pacc;
    sH[c][dl][n] = h;
    __syncthreads();    // the only cross-wave exchange (sP/sH)

    // ---- phase B: carry-in correction for chunks 1..15 (32 j) ----
    if (c > 0) {
        float hs = 0.f;
        for (int s = 0; s < c; ++s)
            hs = fmaf(sP[s][dl][n], hs, sH[s][dl][n]);
        float gv = hs;
        float rc2[8];
#pragma unroll
        for (int q = 0; q < 8; ++q) rc2[q] = xbn[q * XPROJ_N + N_STATE];
#pragma unroll
        for (int g = 0; g < SCH / 8; ++g) {
            float nc2[8];
            if (g + 1 < SCH / 8) {
#pragma unroll
                for (int q = 0; q < 8; ++q)
                    nc2[q] = xbn[(g * 8 + 8 + q) * XPROJ_N + N_STATE];
            }
#pragma unroll
            for (int q = 0; q < 8; ++q) {
                const int j = g * 8 + q;
                float dv = sd[c][j][dl];
                gv *= __expf(dv * Av);
                float p = gv * rc2[q];
                p = dpp_radd<0x128>(p);
                p = dpp_radd<0x124>(p);
                p = dpp_radd<0x122>(p);
                p = dpp_radd<0x121>(p);
                if (n == 0) sy[c][j][dl] += p;
            }
#pragma unroll
            for (int q = 0; q < 8; ++q) rc2[q] = nc2[q];
        }
    }
    wave_lds_fence();   // sy for chunks {2w,2w+1} is wave-private

    // ---- phase C: gate with silu(res) and emit bf16 ----
    {
        float2 yv = *(const float2*)&sy[tc][tj][0];
        float o0 = yv.x * silu_f(rv.x);
        float o1 = yv.y * silu_f(rv.y);
        *(unsigned*)(ybf + trow * D_INNER + d0) = pack2bf(o0, o1);
    }
}

// ---------------------------------------------------------------------------
extern "C" void kernel_launch(void* const* d_in, const int* in_sizes, int n_in,
                              void* d_out, int out_size, void* d_ws, size_t ws_size,
                              hipStream_t stream)
{
    const float* input_ids = (const float*)d_in[0];
    const float* fc_W      = (const float*)d_in[1];
    const float* fc_b      = (const float*)d_in[2];
    const float* in_proj_W = (const float*)d_in[3];
    const float* conv_W    = (const float*)d_in[4];
    const float* conv_b    = (const float*)d_in[5];
    const float* x_proj_W  = (const float*)d_in[6];
    const float* dt_proj_W = (const float*)d_in[7];
    const float* dt_proj_b = (const float*)d_in[8];
    const float* A_log     = (const float*)d_in[9];
    const float* Dp        = (const float*)d_in[10];
    const float* out_proj_W= (const float*)d_in[11];
    const float* norm_W    = (const float*)d_in[12];
    const float* normf_W   = (const float*)d_in[13];
    const float* head_W    = (const float*)d_in[14];
    float* out = (float*)d_out;

    float* ws       = (float*)d_ws;
    // f32 region: x_ws + per-layer xdbl contiguous (single zero span), then xz, u.
    float* x_ws     = ws;                                        // M*384
    float* xdbl_ws  = x_ws    + (size_t)MROWS * D_MODEL;         // 4 * M*56
    float* xz_ws    = xdbl_ws + (size_t)N_LAYER * MROWS * XPROJ_N; // M*1536
    float* u_ws     = xz_ws   + (size_t)MROWS * 2 * D_INNER;     // M*768
    // bf16 region
    short* bf       = (short*)(u_ws + (size_t)MROWS * D_INNER);
    short* wbf_fc   = bf;
    short* wbf_in   = wbf_fc  + (size_t)D_MODEL * VOCAB;
    short* wbf_x    = wbf_in  + (size_t)N_LAYER * 2 * D_INNER * D_MODEL;
    short* wbf_out  = wbf_x   + (size_t)N_LAYER * XPROJ_N * D_INNER;
    short* wbf_head = wbf_out + (size_t)N_LAYER * D_MODEL * D_INNER;
    short* ids_bf   = wbf_head+ (size_t)FEAT * D_MODEL;
    short* ubf_ws   = ids_bf  + (size_t)MROWS * VOCAB;
    short* ybf_ws   = ubf_ws  + (size_t)MROWS * D_INNER;

    const dim3 blk(256);
    const dim3 blk512(512);

    // --- one-shot cast to bf16 (weights + input_ids) + zero atomic dst buffers ---
    CastDesc cd;
    cd.src[0] = fc_W;       cd.dst[0] = wbf_fc;
    cd.src[1] = in_proj_W;  cd.dst[1] = wbf_in;
    cd.src[2] = x_proj_W;   cd.dst[2] = wbf_x;
    cd.src[3] = out_proj_W; cd.dst[3] = wbf_out;
    cd.src[4] = head_W;     cd.dst[4] = wbf_head;
    cd.src[5] = input_ids;  cd.dst[5] = ids_bf;
    unsigned c0 = (unsigned)(D_MODEL * VOCAB / 4);
    unsigned c1 = c0 + (unsigned)(N_LAYER * 2 * D_INNER * D_MODEL / 4);
    unsigned c2 = c1 + (unsigned)(N_LAYER * XPROJ_N * D_INNER / 4);
    unsigned c3 = c2 + (unsigned)(N_LAYER * D_MODEL * D_INNER / 4);
    unsigned c4 = c3 + (unsigned)(FEAT * D_MODEL / 4);
    unsigned c5 = c4 + (unsigned)(MROWS * VOCAB / 4);
    cd.cum[0] = c0; cd.cum[1] = c1; cd.cum[2] = c2;
    cd.cum[3] = c3; cd.cum[4] = c4; cd.cum[5] = c5;
    const unsigned zero4 = (unsigned)((MROWS * D_MODEL + N_LAYER * MROWS * XPROJ_N) / 4);
    cast_w_k<<<(c5 + zero4 + 255) / 256, blk, 0, stream>>>(cd, c5, (float4*)x_ws, zero4);

    // x = input_ids @ fc_W.T + fc_b   (A pre-cast bf16, split-K=7, atomic)
    mfma_gemm<1, false, true, false, false, true><<<dim3(D_MODEL / 64, MROWS / 64, 7), blk, 0, stream>>>(
        nullptr, ids_bf, wbf_fc, fc_b, nullptr, nullptr, x_ws,
        MROWS, D_MODEL, VOCAB, VOCAB, 0, D_MODEL, 256);

    for (int i = 0; i < N_LAYER; ++i) {
        float* xdbl_i = xdbl_ws + (size_t)i * MROWS * XPROJ_N;

        // xz = rmsnorm(x, norm_W) @ in_proj_W.T   (rmsnorm fused into A staging)
        mfma_gemm<0, false, false, true, false, false><<<dim3(2 * D_INNER / 64, MROWS / 64, 1), blk, 0, stream>>>(
            x_ws, nullptr, wbf_in + (size_t)i * 2 * D_INNER * D_MODEL,
            nullptr, nullptr, norm_W + i * D_MODEL, xz_ws,
            MROWS, 2 * D_INNER, D_MODEL, D_MODEL, 0, 2 * D_INNER, D_MODEL);

        // u = silu(conv(xz[:, :768]) + conv_b)  (f32 + bf16 copies)
        conv_silu_k<<<(MROWS * (D_INNER / 4) + 255) / 256, blk, 0, stream>>>(
            xz_ws, conv_W + (size_t)i * D_INNER * D_CONV, conv_b + i * D_INNER,
            u_ws, ubf_ws);

        // x_dbl = u @ x_proj_W[i].T  (A pre-cast bf16, N=56 guarded, split-K=6,
        // dst pre-zeroed once in cast_w_k -- per-layer buffer)
        mfma_gemm<0, false, true, false, true, true><<<dim3(1, MROWS / 64, 6), blk, 0, stream>>>(
            nullptr, ubf_ws, wbf_x + (size_t)i * XPROJ_N * D_INNER,
            nullptr, nullptr, nullptr, xdbl_i,
            MROWS, XPROJ_N, D_INNER, D_INNER, 0, XPROJ_N, 128);

        // fused: dt_proj+softplus -> two-phase chunked scan -> gate -> ybf (bf16)
        scan_fused_k<<<dim3(D_INNER / DG, B_), blk512, 0, stream>>>(
            xdbl_i, u_ws, xz_ws,
            dt_proj_W + (size_t)i * D_INNER * DT_RANK, dt_proj_b + i * D_INNER,
            A_log + (size_t)i * D_INNER * N_STATE, Dp + i * D_INNER, ybf_ws);

        // x += ybf @ out_proj_W.T  (A pre-cast bf16 gated y, split-K=2, atomic residual)
        mfma_gemm<0, false, true, false, false, true><<<dim3(D_MODEL / 64, MROWS / 64, 2), blk, 0, stream>>>(
            nullptr, ybf_ws, wbf_out + (size_t)i * D_MODEL * D_INNER,
            nullptr, nullptr, nullptr, x_ws,
            MROWS, D_MODEL, D_INNER, D_INNER, 0, D_MODEL, 384);
    }

    // out = rmsnorm(x, normf_W) @ head_W.T  (rmsnorm fused)
    mfma_gemm<0, false, false, true, false, false><<<dim3(FEAT / 64, MROWS / 64, 1), blk, 0, stream>>>(
        x_ws, nullptr, wbf_head, nullptr, nullptr, normf_W, out,
        MROWS, FEAT, D_MODEL, D_MODEL, 0, FEAT, D_MODEL);
}

// Round 5
// 521.235 us; speedup vs baseline: 1.1242x; 1.0658x over previous
//
#include <hip/hip_runtime.h>
#include <math.h>

// Problem dims
#define B_ 4
#define L_ 512
#define MROWS 2048
#define D_MODEL 384
#define N_LAYER 4
#define D_INNER 768
#define N_STATE 16
#define DT_RANK 24
#define D_CONV 4
#define VOCAB 1544
#define FEAT 1536
#define XPROJ_N 56
#define NCH 16              // scan chunks per batch (L/32)
#define SCH 32              // scan chunk length
#define DG 2                // d-channels per scan block

typedef __attribute__((ext_vector_type(8))) short short8;
typedef __attribute__((ext_vector_type(4))) float floatx4;

__device__ __forceinline__ float softplus_f(float x) { return x > 20.f ? x : log1pf(expf(x)); }
__device__ __forceinline__ float silu_f(float x) { return x / (1.f + __expf(-x)); }

// f32 -> bf16 (RNE), two packed into one u32
__device__ __forceinline__ unsigned pack2bf(float x, float y) {
    unsigned ux = __float_as_uint(x); ux = (ux + 0x7FFFu + ((ux >> 16) & 1u)) >> 16;
    unsigned uy = __float_as_uint(y); uy = (uy + 0x7FFFu + ((uy >> 16) & 1u)) >> 16;
    return ux | (uy << 16);
}

// DPP row-rotate add: x + (x ror N within each 16-lane row). After ror
// 8,4,2,1 every lane holds the full 16-sum.
template <int CTRL>
__device__ __forceinline__ float dpp_radd(float x) {
    int r = __builtin_amdgcn_update_dpp(0, __float_as_int(x), CTRL, 0xf, 0xf, true);
    return x + __int_as_float(r);
}

// Wave-local LDS fence: producer and consumer are the SAME wave (cross-lane
// ok) -- s_waitcnt makes the wave's own ds_writes visible, wave_barrier pins
// ordering. Replaces __syncthreads where no cross-wave data flows.
__device__ __forceinline__ void wave_lds_fence() {
    asm volatile("s_waitcnt lgkmcnt(0)" ::: "memory");
    __builtin_amdgcn_wave_barrier();
}

__device__ __forceinline__ float4 ld4_guard(const float* __restrict__ p, int k, int ke) {
    if (k + 3 < ke) return *(const float4*)(p + k);
    float4 r = make_float4(0.f, 0.f, 0.f, 0.f);
    if (k + 0 < ke) r.x = p[k + 0];
    if (k + 1 < ke) r.y = p[k + 1];
    if (k + 2 < ke) r.z = p[k + 2];
    return r;
}

__device__ __forceinline__ short8 ld8h_guard(const short* __restrict__ p, int k, int ke) {
    if (k + 7 < ke) return *(const short8*)(p + k);
    short8 r = {0, 0, 0, 0, 0, 0, 0, 0};
#pragma unroll
    for (int j = 0; j < 8; ++j)
        if (k + j < ke) r[j] = p[k + j];
    return r;
}

// ---------------------------------------------------------------------------
// One-shot weight/input cast f32 -> bf16 + grid-stride zeroing of atomic dsts.
// ---------------------------------------------------------------------------
struct CastDesc {
    const float* src[6];
    short*       dst[6];
    unsigned     cum[6];   // exclusive prefix ends, in float4 units
};

__global__ __launch_bounds__(256) void cast_w_k(CastDesc cd, unsigned total4,
                                                float4* __restrict__ zb, unsigned z4)
{
    unsigned i = blockIdx.x * 256 + threadIdx.x;
    if (i < total4) {
        int s = 0;
#pragma unroll
        for (int j = 0; j < 5; ++j)
            if (i >= cd.cum[j] && s == j) s = j + 1;
        unsigned off = i - (s ? cd.cum[s - 1] : 0u);
        float4 v = ((const float4*)cd.src[s])[off];
        uint2 pk;
        pk.x = pack2bf(v.x, v.y);
        pk.y = pack2bf(v.z, v.w);
        ((uint2*)cd.dst[s])[off] = pk;
    } else {
        unsigned zi = i - total4;
        if (zi < z4) zb[zi] = make_float4(0.f, 0.f, 0.f, 0.f);
    }
}

// ---------------------------------------------------------------------------
// MFMA bf16 GEMM: C[m,n] (+)= sum_k A[m,k]*W[n,k].  W pre-cast bf16.
// Pipelined K-loop: stage(k+1) -> prefetch(k+2) -> MFMA(k) -> barrier.
// ABF: A pre-cast bf16. EPI: 0 none, 1 +bias(z==0 if ATOMIC), 2 softplus+bias.
// ---------------------------------------------------------------------------
#define ASTR 40

template <int EPI, bool GATED, bool ATOMIC, bool RMSN, bool NG, bool ABF>
__global__ __launch_bounds__(256) void mfma_gemm(
    const float* __restrict__ A, const short* __restrict__ Abf,
    const short* __restrict__ Wb,
    const float* __restrict__ bias, const float* __restrict__ gate,
    const float* __restrict__ nw,
    float* __restrict__ C, int M, int N, int K, int lda, int ldg, int ldc, int KC)
{
    __shared__ short As[2][64 * ASTR];
    __shared__ short Ws[2][64 * ASTR];
    __shared__ float sscale[64];

    const int t  = threadIdx.x;
    const int m0 = blockIdx.y * 64;
    const int n0 = blockIdx.x * 64;
    const int ks = blockIdx.z * KC;
    const int ke = min(K, ks + KC);

    const int srow = t >> 2;           // 0..63
    const int sseg = (t & 3) * 8;      // 0,8,16,24

    if (RMSN) {
        const int row = t >> 2, q = t & 3;
        const float* xr = A + (size_t)(m0 + row) * lda + q * (K >> 2);
        float s = 0.f;
        for (int i = 0; i < (K >> 2); i += 4) {
            float4 v = *(const float4*)(xr + i);
            s += v.x * v.x + v.y * v.y + v.z * v.z + v.w * v.w;
        }
        s += __shfl_xor(s, 1, 64);
        s += __shfl_xor(s, 2, 64);
        if (q == 0) sscale[row] = rsqrtf(s / (float)K + 1e-5f);
        __syncthreads();
    }

    float4 ra0, ra1, rg0, rg1, rn0, rn1;
    short8 ra8, rw8;

    auto prefetch = [&](int k0) {
        if (ABF) {
            ra8 = ld8h_guard(Abf + (size_t)(m0 + srow) * lda, k0 + sseg, ke);
        } else {
            const float* ar = A + (size_t)(m0 + srow) * lda;
            ra0 = ld4_guard(ar, k0 + sseg, ke);
            ra1 = ld4_guard(ar, k0 + sseg + 4, ke);
            if (GATED) {
                const float* gr = gate + (size_t)(m0 + srow) * ldg;
                rg0 = ld4_guard(gr, k0 + sseg, ke);
                rg1 = ld4_guard(gr, k0 + sseg + 4, ke);
            }
            if (RMSN) {
                rn0 = ld4_guard(nw, k0 + sseg, ke);
                rn1 = ld4_guard(nw, k0 + sseg + 4, ke);
            }
        }
        if (!NG || (n0 + srow) < N) {
            rw8 = ld8h_guard(Wb + (size_t)(n0 + srow) * (size_t)K, k0 + sseg, ke);
        } else {
            rw8 = (short8){0, 0, 0, 0, 0, 0, 0, 0};
        }
    };

    auto stage = [&](int p) {
        if (ABF) {
            *(short8*)&As[p][srow * ASTR + sseg] = ra8;
        } else {
            float4 a0 = ra0, a1 = ra1;
            if (GATED) {
                a0.x *= silu_f(rg0.x); a0.y *= silu_f(rg0.y); a0.z *= silu_f(rg0.z); a0.w *= silu_f(rg0.w);
                a1.x *= silu_f(rg1.x); a1.y *= silu_f(rg1.y); a1.z *= silu_f(rg1.z); a1.w *= silu_f(rg1.w);
            }
            if (RMSN) {
                float sc = sscale[srow];
                a0.x *= sc * rn0.x; a0.y *= sc * rn0.y; a0.z *= sc * rn0.z; a0.w *= sc * rn0.w;
                a1.x *= sc * rn1.x; a1.y *= sc * rn1.y; a1.z *= sc * rn1.z; a1.w *= sc * rn1.w;
            }
            int4 pa;
            pa.x = pack2bf(a0.x, a0.y); pa.y = pack2bf(a0.z, a0.w);
            pa.z = pack2bf(a1.x, a1.y); pa.w = pack2bf(a1.z, a1.w);
            *(int4*)&As[p][srow * ASTR + sseg] = pa;
        }
        *(short8*)&Ws[p][srow * ASTR + sseg] = rw8;
    };

    prefetch(ks);
    stage(0);
    if (ks + 32 < ke) prefetch(ks + 32);   // loads for iter 2 in flight across barrier
    __syncthreads();

    floatx4 acc[2][2];
#pragma unroll
    for (int i = 0; i < 2; ++i)
#pragma unroll
        for (int j = 0; j < 2; ++j) acc[i][j] = (floatx4){0.f, 0.f, 0.f, 0.f};

    const int w    = t >> 6;
    const int lane = t & 63;
    const int quad = lane >> 4;
    const int lm   = lane & 15;
    const int aoff = ((w >> 1) * 32 + lm) * ASTR + quad * 8;
    const int boff = ((w & 1) * 32 + lm) * ASTR + quad * 8;

    int p = 0;
    for (int k0 = ks; k0 < ke; k0 += 32) {
        const bool more = (k0 + 32 < ke);
        if (more) {
            stage(p ^ 1);                       // consumes loads issued 1 iter ago
            if (k0 + 64 < ke) prefetch(k0 + 64); // issue 2 iters ahead
        }
        short8 a0 = *(const short8*)&As[p][aoff];
        short8 a1 = *(const short8*)&As[p][aoff + 16 * ASTR];
        short8 b0 = *(const short8*)&Ws[p][boff];
        short8 b1 = *(const short8*)&Ws[p][boff + 16 * ASTR];
        acc[0][0] = __builtin_amdgcn_mfma_f32_16x16x32_bf16(a0, b0, acc[0][0], 0, 0, 0);
        acc[0][1] = __builtin_amdgcn_mfma_f32_16x16x32_bf16(a0, b1, acc[0][1], 0, 0, 0);
        acc[1][0] = __builtin_amdgcn_mfma_f32_16x16x32_bf16(a1, b0, acc[1][0], 0, 0, 0);
        acc[1][1] = __builtin_amdgcn_mfma_f32_16x16x32_bf16(a1, b1, acc[1][1], 0, 0, 0);
        if (more) {
            __syncthreads();
            p ^= 1;
        }
    }

    const int rbase = m0 + (w >> 1) * 32 + quad * 4;
    const int cbase = n0 + (w & 1) * 32 + lm;
#pragma unroll
    for (int mt = 0; mt < 2; ++mt)
#pragma unroll
        for (int nt = 0; nt < 2; ++nt) {
            const int gc = cbase + nt * 16;
            if (NG && gc >= N) continue;
#pragma unroll
            for (int r = 0; r < 4; ++r) {
                const size_t gr = rbase + mt * 16 + r;
                float v = acc[mt][nt][r];
                if (ATOMIC) {
                    if (EPI == 1 && blockIdx.z == 0) v += bias[gc];
                    atomicAdd(&C[gr * ldc + gc], v);
                } else {
                    if (EPI == 1) v += bias[gc];
                    if (EPI == 2) v = softplus_f(v + bias[gc]);
                    C[gr * ldc + gc] = v;
                }
            }
        }
}

// ---------------------------------------------------------------------------
// Depthwise causal conv (width 4) + bias + SiLU; writes u (f32) and u_bf.
// ---------------------------------------------------------------------------
__global__ __launch_bounds__(256) void conv_silu_k(
    const float* __restrict__ xz, const float* __restrict__ w,
    const float* __restrict__ cb, float* __restrict__ u, short* __restrict__ ubf)
{
    int idx = blockIdx.x * 256 + threadIdx.x;
    if (idx >= MROWS * (D_INNER / 4)) return;
    int dq = idx % (D_INNER / 4);
    int m  = idx / (D_INNER / 4);
    int d0 = dq * 4;
    int b = m / L_, l = m % L_;
    float4 wq[4];
#pragma unroll
    for (int j = 0; j < 4; ++j) wq[j] = *(const float4*)(w + (d0 + j) * D_CONV);
    float acc[4];
#pragma unroll
    for (int j = 0; j < 4; ++j) acc[j] = cb[d0 + j];
#pragma unroll
    for (int tt = 0; tt < 4; ++tt) {
        int ll = l - 3 + tt;
        if (ll >= 0) {
            float4 xv = *(const float4*)(xz + (size_t)(b * L_ + ll) * (2 * D_INNER) + d0);
            acc[0] = fmaf(xv.x, ((const float*)&wq[0])[tt], acc[0]);
            acc[1] = fmaf(xv.y, ((const float*)&wq[1])[tt], acc[1]);
            acc[2] = fmaf(xv.z, ((const float*)&wq[2])[tt], acc[2]);
            acc[3] = fmaf(xv.w, ((const float*)&wq[3])[tt], acc[3]);
        }
    }
    float4 o = make_float4(silu_f(acc[0]), silu_f(acc[1]), silu_f(acc[2]), silu_f(acc[3]));
    *(float4*)(u + (size_t)m * D_INNER + d0) = o;
    uint2 pk;
    pk.x = pack2bf(o.x, o.y);
    pk.y = pack2bf(o.z, o.w);
    *(uint2*)(ubf + (size_t)m * D_INNER + d0) = pk;
}

// ---------------------------------------------------------------------------
// Fused selective scan, r5: carry-folded two-pass (r4 showed dur pinned by
// VALU count -- phaseA+phaseB did the DPP reduction TWICE, ~29 VALU/j).
//   phase 0: stage u, delta = softplus(dt-dot) f32, early xz gate load
//   pass 1 : P/H only, NO reduction (~6 VALU/j); P = exp(Av*sum(dv))
//   barrier (only one): sP/sH exchange; pass-2 group-0 B/C loads issued
//            BEFORE the barrier to cover it
//   carry  : hs = fold(P,H) over preceding chunks
//   pass 2 : full recurrence with h INITIALIZED to hs -> y is final
//            directly (one DPP reduce total, ~14 VALU/j)
//   phase C: gate + bf16 emit (coalesced row-task mapping)
// ---------------------------------------------------------------------------
__global__ __launch_bounds__(512, 4) void scan_fused_k(
    const float* __restrict__ xdbl, const float* __restrict__ u,
    const float* __restrict__ xz,
    const float* __restrict__ dtW, const float* __restrict__ dtb,
    const float* __restrict__ A_log, const float* __restrict__ Dp,
    short* __restrict__ ybf)
{
    __shared__ __align__(16) float sd[NCH][SCH][DG];        // 4KB
    __shared__ __align__(16) float su[NCH][SCH][DG];        // 4KB
    __shared__ __align__(16) float sy[NCH][SCH][DG];        // 4KB
    __shared__ float sP[NCH][DG][16], sH[NCH][DG][16];      // 4KB

    const int t  = threadIdx.x;
    const int w  = t >> 6;          // wave 0..7
    const int l  = t & 63;
    const int ch = l >> 5;          // 0..1 -> which of the wave's two chunks
    const int c  = w * 2 + ch;      // chunk 0..15
    const int dl = (l >> 4) & 1;    // channel within block
    const int n  = l & 15;          // state index
    // XCD-chunked swizzle (bijective, 384 = 8 * 48): adjacent d-groups share
    // cache lines of u/xz/ybf -> keep them on one XCD (r1: FETCH 51->8MB).
    const int bx  = blockIdx.x;
    const int dgi = (bx & 7) * (D_INNER / DG / 8) + (bx >> 3);
    const int d0 = dgi * DG;
    const int d  = d0 + dl;
    const int b  = blockIdx.y;

    // row-task mapping (each thread owns one global row for staging/phase C)
    const int tc = t >> 5, tj = t & 31;          // tc in {2w, 2w+1} -> wave-private
    const size_t trow = (size_t)b * L_ + t;

    // ---- phase 0: wave-private staging ----
    // early-issue phase-C gate load (consumed ~3000cy later)
    float2 rv  = *(const float2*)(xz + trow * (2 * D_INNER) + D_INNER + d0);
    float2 uv2 = *(const float2*)(u + trow * D_INNER + d0);
    *(float2*)&su[tc][tj][0] = uv2;

    // delta = softplus(xdbl[:, :24] @ dtW.T + dtb) in f32; each lane does
    // rows {2n, 2n+1} of its chunk c for channel d.
    {
        float4 w4[6];
#pragma unroll
        for (int q = 0; q < 6; ++q) w4[q] = *(const float4*)(dtW + (size_t)d * DT_RANK + q * 4);
        const float bias = dtb[d];
#pragma unroll
        for (int rr = 0; rr < 2; ++rr) {
            const int j = n * 2 + rr;
            const float* xr = xdbl + ((size_t)b * L_ + c * SCH + j) * XPROJ_N;
            float acc = bias;
#pragma unroll
            for (int q = 0; q < 6; ++q) {
                float4 xv = *(const float4*)(xr + q * 4);
                acc = fmaf(xv.x, w4[q].x, acc);
                acc = fmaf(xv.y, w4[q].y, acc);
                acc = fmaf(xv.z, w4[q].z, acc);
                acc = fmaf(xv.w, w4[q].w, acc);
            }
            sd[c][j][dl] = softplus_f(acc);
        }
    }
    wave_lds_fence();   // sd/su for chunks {2w,2w+1} produced+consumed by wave w

    const float Av = -expf(A_log[d * N_STATE + n]);
    const float Dd = Dp[d];
    const float* xbn = xdbl + ((size_t)b * L_ + c * SCH) * XPROJ_N + DT_RANK + n;

    // ---- pass 1: chunk-local end-state H and decay product P (no reduce) ----
    {
        float h = 0.f, sdv = 0.f;
        float rB[8];
#pragma unroll
        for (int q = 0; q < 8; ++q) rB[q] = xbn[q * XPROJ_N];
#pragma unroll
        for (int g = 0; g < SCH / 8; ++g) {
            float nB[8];
            if (g + 1 < SCH / 8) {
#pragma unroll
                for (int q = 0; q < 8; ++q) nB[q] = xbn[(g * 8 + 8 + q) * XPROJ_N];
            }
#pragma unroll
            for (int q = 0; q < 8; ++q) {
                const int j = g * 8 + q;
                float dv = sd[c][j][dl];
                float uv = su[c][j][dl];
                float e  = __expf(dv * Av);
                h = fmaf(e, h, dv * uv * rB[q]);
                sdv += dv;
            }
#pragma unroll
            for (int q = 0; q < 8; ++q) rB[q] = nB[q];
        }
        sP[c][dl][n] = __expf(sdv * Av);   // prod of exps = exp of sum
        sH[c][dl][n] = h;
    }

    // issue pass-2 group-0 B/C loads BEFORE the barrier (latency cover)
    float rB[8], rC[8];
#pragma unroll
    for (int q = 0; q < 8; ++q) {
        rB[q] = xbn[q * XPROJ_N];
        rC[q] = xbn[q * XPROJ_N + N_STATE];
    }
    __syncthreads();    // the only cross-wave exchange (sP/sH)

    // ---- carry-in: hs = fold over preceding chunks ----
    float hs = 0.f;
    for (int s = 0; s < c; ++s)
        hs = fmaf(sP[s][dl][n], hs, sH[s][dl][n]);

    // ---- pass 2: full recurrence from h=hs; y is final directly ----
    {
        float h = hs;
#pragma unroll
        for (int g = 0; g < SCH / 8; ++g) {
            float nB[8], nC[8];
            if (g + 1 < SCH / 8) {
#pragma unroll
                for (int q = 0; q < 8; ++q) {
                    nB[q] = xbn[(g * 8 + 8 + q) * XPROJ_N];
                    nC[q] = xbn[(g * 8 + 8 + q) * XPROJ_N + N_STATE];
                }
            }
#pragma unroll
            for (int q = 0; q < 8; ++q) {
                const int j = g * 8 + q;
                float dv = sd[c][j][dl];
                float uv = su[c][j][dl];
                float e  = __expf(dv * Av);
                h = fmaf(e, h, dv * uv * rB[q]);
                float p = h * rC[q];
                p = dpp_radd<0x128>(p);
                p = dpp_radd<0x124>(p);
                p = dpp_radd<0x122>(p);
                p = dpp_radd<0x121>(p);
                if (n == 0) sy[c][j][dl] = fmaf(uv, Dd, p);
            }
#pragma unroll
            for (int q = 0; q < 8; ++q) { rB[q] = nB[q]; rC[q] = nC[q]; }
        }
    }
    wave_lds_fence();   // sy for chunks {2w,2w+1} is wave-private

    // ---- phase C: gate with silu(res) and emit bf16 ----
    {
        float2 yv = *(const float2*)&sy[tc][tj][0];
        float o0 = yv.x * silu_f(rv.x);
        float o1 = yv.y * silu_f(rv.y);
        *(unsigned*)(ybf + trow * D_INNER + d0) = pack2bf(o0, o1);
    }
}

// ---------------------------------------------------------------------------
extern "C" void kernel_launch(void* const* d_in, const int* in_sizes, int n_in,
                              void* d_out, int out_size, void* d_ws, size_t ws_size,
                              hipStream_t stream)
{
    const float* input_ids = (const float*)d_in[0];
    const float* fc_W      = (const float*)d_in[1];
    const float* fc_b      = (const float*)d_in[2];
    const float* in_proj_W = (const float*)d_in[3];
    const float* conv_W    = (const float*)d_in[4];
    const float* conv_b    = (const float*)d_in[5];
    const float* x_proj_W  = (const float*)d_in[6];
    const float* dt_proj_W = (const float*)d_in[7];
    const float* dt_proj_b = (const float*)d_in[8];
    const float* A_log     = (const float*)d_in[9];
    const float* Dp        = (const float*)d_in[10];
    const float* out_proj_W= (const float*)d_in[11];
    const float* norm_W    = (const float*)d_in[12];
    const float* normf_W   = (const float*)d_in[13];
    const float* head_W    = (const float*)d_in[14];
    float* out = (float*)d_out;

    float* ws       = (float*)d_ws;
    // f32 region: x_ws + per-layer xdbl contiguous (single zero span), then xz, u.
    float* x_ws     = ws;                                        // M*384
    float* xdbl_ws  = x_ws    + (size_t)MROWS * D_MODEL;         // 4 * M*56
    float* xz_ws    = xdbl_ws + (size_t)N_LAYER * MROWS * XPROJ_N; // M*1536
    float* u_ws     = xz_ws   + (size_t)MROWS * 2 * D_INNER;     // M*768
    // bf16 region
    short* bf       = (short*)(u_ws + (size_t)MROWS * D_INNER);
    short* wbf_fc   = bf;
    short* wbf_in   = wbf_fc  + (size_t)D_MODEL * VOCAB;
    short* wbf_x    = wbf_in  + (size_t)N_LAYER * 2 * D_INNER * D_MODEL;
    short* wbf_out  = wbf_x   + (size_t)N_LAYER * XPROJ_N * D_INNER;
    short* wbf_head = wbf_out + (size_t)N_LAYER * D_MODEL * D_INNER;
    short* ids_bf   = wbf_head+ (size_t)FEAT * D_MODEL;
    short* ubf_ws   = ids_bf  + (size_t)MROWS * VOCAB;
    short* ybf_ws   = ubf_ws  + (size_t)MROWS * D_INNER;

    const dim3 blk(256);
    const dim3 blk512(512);

    // --- one-shot cast to bf16 (weights + input_ids) + zero atomic dst buffers ---
    CastDesc cd;
    cd.src[0] = fc_W;       cd.dst[0] = wbf_fc;
    cd.src[1] = in_proj_W;  cd.dst[1] = wbf_in;
    cd.src[2] = x_proj_W;   cd.dst[2] = wbf_x;
    cd.src[3] = out_proj_W; cd.dst[3] = wbf_out;
    cd.src[4] = head_W;     cd.dst[4] = wbf_head;
    cd.src[5] = input_ids;  cd.dst[5] = ids_bf;
    unsigned c0 = (unsigned)(D_MODEL * VOCAB / 4);
    unsigned c1 = c0 + (unsigned)(N_LAYER * 2 * D_INNER * D_MODEL / 4);
    unsigned c2 = c1 + (unsigned)(N_LAYER * XPROJ_N * D_INNER / 4);
    unsigned c3 = c2 + (unsigned)(N_LAYER * D_INNER * DT_RANK / 4 * 0 + N_LAYER * D_MODEL * D_INNER / 4);
    unsigned c4 = c3 + (unsigned)(FEAT * D_MODEL / 4);
    unsigned c5 = c4 + (unsigned)(MROWS * VOCAB / 4);
    cd.cum[0] = c0; cd.cum[1] = c1; cd.cum[2] = c2;
    cd.cum[3] = c3; cd.cum[4] = c4; cd.cum[5] = c5;
    const unsigned zero4 = (unsigned)((MROWS * D_MODEL + N_LAYER * MROWS * XPROJ_N) / 4);
    cast_w_k<<<(c5 + zero4 + 255) / 256, blk, 0, stream>>>(cd, c5, (float4*)x_ws, zero4);

    // x = input_ids @ fc_W.T + fc_b   (A pre-cast bf16, split-K=7, atomic)
    mfma_gemm<1, false, true, false, false, true><<<dim3(D_MODEL / 64, MROWS / 64, 7), blk, 0, stream>>>(
        nullptr, ids_bf, wbf_fc, fc_b, nullptr, nullptr, x_ws,
        MROWS, D_MODEL, VOCAB, VOCAB, 0, D_MODEL, 256);

    for (int i = 0; i < N_LAYER; ++i) {
        float* xdbl_i = xdbl_ws + (size_t)i * MROWS * XPROJ_N;

        // xz = rmsnorm(x, norm_W) @ in_proj_W.T   (rmsnorm fused into A staging)
        mfma_gemm<0, false, false, true, false, false><<<dim3(2 * D_INNER / 64, MROWS / 64, 1), blk, 0, stream>>>(
            x_ws, nullptr, wbf_in + (size_t)i * 2 * D_INNER * D_MODEL,
            nullptr, nullptr, norm_W + i * D_MODEL, xz_ws,
            MROWS, 2 * D_INNER, D_MODEL, D_MODEL, 0, 2 * D_INNER, D_MODEL);

        // u = silu(conv(xz[:, :768]) + conv_b)  (f32 + bf16 copies)
        conv_silu_k<<<(MROWS * (D_INNER / 4) + 255) / 256, blk, 0, stream>>>(
            xz_ws, conv_W + (size_t)i * D_INNER * D_CONV, conv_b + i * D_INNER,
            u_ws, ubf_ws);

        // x_dbl = u @ x_proj_W[i].T  (A pre-cast bf16, N=56 guarded, split-K=6,
        // dst pre-zeroed once in cast_w_k -- per-layer buffer)
        mfma_gemm<0, false, true, false, true, true><<<dim3(1, MROWS / 64, 6), blk, 0, stream>>>(
            nullptr, ubf_ws, wbf_x + (size_t)i * XPROJ_N * D_INNER,
            nullptr, nullptr, nullptr, xdbl_i,
            MROWS, XPROJ_N, D_INNER, D_INNER, 0, XPROJ_N, 128);

        // fused: dt_proj+softplus -> carry-folded two-pass scan -> gate -> ybf
        scan_fused_k<<<dim3(D_INNER / DG, B_), blk512, 0, stream>>>(
            xdbl_i, u_ws, xz_ws,
            dt_proj_W + (size_t)i * D_INNER * DT_RANK, dt_proj_b + i * D_INNER,
            A_log + (size_t)i * D_INNER * N_STATE, Dp + i * D_INNER, ybf_ws);

        // x += ybf @ out_proj_W.T  (A pre-cast bf16 gated y, split-K=2, atomic residual)
        mfma_gemm<0, false, true, false, false, true><<<dim3(D_MODEL / 64, MROWS / 64, 2), blk, 0, stream>>>(
            nullptr, ybf_ws, wbf_out + (size_t)i * D_MODEL * D_INNER,
            nullptr, nullptr, nullptr, x_ws,
            MROWS, D_MODEL, D_INNER, D_INNER, 0, D_MODEL, 384);
    }

    // out = rmsnorm(x, normf_W) @ head_W.T  (rmsnorm fused)
    mfma_gemm<0, false, false, true, false, false><<<dim3(FEAT / 64, MROWS / 64, 1), blk, 0, stream>>>(
        x_ws, nullptr, wbf_head, nullptr, nullptr, normf_W, out,
        MROWS, FEAT, D_MODEL, D_MODEL, 0, FEAT, D_MODEL);
}

// Round 6
// 428.463 us; speedup vs baseline: 1.3676x; 1.2165x over previous
//
#include <hip/hip_runtime.h>
#include <math.h>

// Problem dims
#define B_ 4
#define L_ 512
#define MROWS 2048
#define D_MODEL 384
#define N_LAYER 4
#define D_INNER 768
#define N_STATE 16
#define DT_RANK 24
#define D_CONV 4
#define VOCAB 1544
#define FEAT 1536
#define XPROJ_N 56
#define NCH 16              // scan chunks per batch (L/32)
#define SCH 32              // scan chunk length
#define DG 2                // d-channels per scan block

typedef __attribute__((ext_vector_type(8))) short short8;
typedef __attribute__((ext_vector_type(4))) float floatx4;

__device__ __forceinline__ float softplus_f(float x) { return x > 20.f ? x : log1pf(expf(x)); }
__device__ __forceinline__ float silu_f(float x) { return x / (1.f + __expf(-x)); }

// f32 -> bf16 (RNE), two packed into one u32
__device__ __forceinline__ unsigned pack2bf(float x, float y) {
    unsigned ux = __float_as_uint(x); ux = (ux + 0x7FFFu + ((ux >> 16) & 1u)) >> 16;
    unsigned uy = __float_as_uint(y); uy = (uy + 0x7FFFu + ((uy >> 16) & 1u)) >> 16;
    return ux | (uy << 16);
}

// DPP row-rotate add: x + (x ror N within each 16-lane row). After ror
// 8,4,2,1 every lane holds the full 16-sum.
template <int CTRL>
__device__ __forceinline__ float dpp_radd(float x) {
    int r = __builtin_amdgcn_update_dpp(0, __float_as_int(x), CTRL, 0xf, 0xf, true);
    return x + __int_as_float(r);
}

// Wave-local LDS fence: producer and consumer are the SAME wave (cross-lane
// ok) -- s_waitcnt makes the wave's own ds_writes visible, wave_barrier pins
// ordering. Replaces __syncthreads where no cross-wave data flows.
__device__ __forceinline__ void wave_lds_fence() {
    asm volatile("s_waitcnt lgkmcnt(0)" ::: "memory");
    __builtin_amdgcn_wave_barrier();
}

__device__ __forceinline__ float4 ld4_guard(const float* __restrict__ p, int k, int ke) {
    if (k + 3 < ke) return *(const float4*)(p + k);
    float4 r = make_float4(0.f, 0.f, 0.f, 0.f);
    if (k + 0 < ke) r.x = p[k + 0];
    if (k + 1 < ke) r.y = p[k + 1];
    if (k + 2 < ke) r.z = p[k + 2];
    return r;
}

__device__ __forceinline__ short8 ld8h_guard(const short* __restrict__ p, int k, int ke) {
    if (k + 7 < ke) return *(const short8*)(p + k);
    short8 r = {0, 0, 0, 0, 0, 0, 0, 0};
#pragma unroll
    for (int j = 0; j < 8; ++j)
        if (k + j < ke) r[j] = p[k + j];
    return r;
}

// ---------------------------------------------------------------------------
// One-shot weight/input cast f32 -> bf16 + grid-stride zeroing of atomic dsts.
// ---------------------------------------------------------------------------
struct CastDesc {
    const float* src[6];
    short*       dst[6];
    unsigned     cum[6];   // exclusive prefix ends, in float4 units
};

__global__ __launch_bounds__(256) void cast_w_k(CastDesc cd, unsigned total4,
                                                float4* __restrict__ zb, unsigned z4)
{
    unsigned i = blockIdx.x * 256 + threadIdx.x;
    if (i < total4) {
        int s = 0;
#pragma unroll
        for (int j = 0; j < 5; ++j)
            if (i >= cd.cum[j] && s == j) s = j + 1;
        unsigned off = i - (s ? cd.cum[s - 1] : 0u);
        float4 v = ((const float4*)cd.src[s])[off];
        uint2 pk;
        pk.x = pack2bf(v.x, v.y);
        pk.y = pack2bf(v.z, v.w);
        ((uint2*)cd.dst[s])[off] = pk;
    } else {
        unsigned zi = i - total4;
        if (zi < z4) zb[zi] = make_float4(0.f, 0.f, 0.f, 0.f);
    }
}

// ---------------------------------------------------------------------------
// RMSNorm + weight scale + bf16 cast, one pass (r6: removes the per-n-block
// rmsnorm recompute inside the GEMM -- each of 24 n-blocks re-read the f32
// slab twice; now GEMMs take the ABF path on this output).
// 8 lanes per row; grid = MROWS*8/256.
// ---------------------------------------------------------------------------
__global__ __launch_bounds__(256) void rmsnorm_cast_k(
    const float* __restrict__ x, const float* __restrict__ nw,
    unsigned* __restrict__ outp)
{
    const int idx = blockIdx.x * 256 + threadIdx.x;
    const int row = idx >> 3, q = idx & 7;
    const float* xr = x + (size_t)row * D_MODEL + q * 48;
    float4 v[12];
    float s = 0.f;
#pragma unroll
    for (int i = 0; i < 12; ++i) {
        v[i] = *(const float4*)(xr + i * 4);
        s += v[i].x * v[i].x + v[i].y * v[i].y + v[i].z * v[i].z + v[i].w * v[i].w;
    }
    s += __shfl_xor(s, 1, 64);
    s += __shfl_xor(s, 2, 64);
    s += __shfl_xor(s, 4, 64);
    const float sc = rsqrtf(s / (float)D_MODEL + 1e-5f);
    unsigned* op = outp + ((size_t)row * D_MODEL + q * 48) / 2;
#pragma unroll
    for (int i = 0; i < 12; ++i) {
        float4 wv = *(const float4*)(nw + q * 48 + i * 4);
        op[i * 2]     = pack2bf(v[i].x * (sc * wv.x), v[i].y * (sc * wv.y));
        op[i * 2 + 1] = pack2bf(v[i].z * (sc * wv.z), v[i].w * (sc * wv.w));
    }
}

// ---------------------------------------------------------------------------
// MFMA bf16 GEMM: C[m,n] (+)= sum_k A[m,k]*W[n,k].  W pre-cast bf16.
// Pipelined K-loop: stage(k+1) -> prefetch(k+2) -> MFMA(k) -> barrier.
// ABF: A pre-cast bf16. EPI: 0 none, 1 +bias(z==0 if ATOMIC), 2 softplus+bias.
// ---------------------------------------------------------------------------
#define ASTR 40

template <int EPI, bool ATOMIC, bool NG, bool ABF>
__global__ __launch_bounds__(256) void mfma_gemm(
    const float* __restrict__ A, const short* __restrict__ Abf,
    const short* __restrict__ Wb,
    const float* __restrict__ bias,
    float* __restrict__ C, int M, int N, int K, int lda, int ldc, int KC)
{
    __shared__ short As[2][64 * ASTR];
    __shared__ short Ws[2][64 * ASTR];

    const int t  = threadIdx.x;
    const int m0 = blockIdx.y * 64;
    const int n0 = blockIdx.x * 64;
    const int ks = blockIdx.z * KC;
    const int ke = min(K, ks + KC);

    const int srow = t >> 2;           // 0..63
    const int sseg = (t & 3) * 8;      // 0,8,16,24

    float4 ra0, ra1;
    short8 ra8, rw8;

    auto prefetch = [&](int k0) {
        if (ABF) {
            ra8 = ld8h_guard(Abf + (size_t)(m0 + srow) * lda, k0 + sseg, ke);
        } else {
            const float* ar = A + (size_t)(m0 + srow) * lda;
            ra0 = ld4_guard(ar, k0 + sseg, ke);
            ra1 = ld4_guard(ar, k0 + sseg + 4, ke);
        }
        if (!NG || (n0 + srow) < N) {
            rw8 = ld8h_guard(Wb + (size_t)(n0 + srow) * (size_t)K, k0 + sseg, ke);
        } else {
            rw8 = (short8){0, 0, 0, 0, 0, 0, 0, 0};
        }
    };

    auto stage = [&](int p) {
        if (ABF) {
            *(short8*)&As[p][srow * ASTR + sseg] = ra8;
        } else {
            int4 pa;
            pa.x = pack2bf(ra0.x, ra0.y); pa.y = pack2bf(ra0.z, ra0.w);
            pa.z = pack2bf(ra1.x, ra1.y); pa.w = pack2bf(ra1.z, ra1.w);
            *(int4*)&As[p][srow * ASTR + sseg] = pa;
        }
        *(short8*)&Ws[p][srow * ASTR + sseg] = rw8;
    };

    prefetch(ks);
    stage(0);
    if (ks + 32 < ke) prefetch(ks + 32);   // loads for iter 2 in flight across barrier
    __syncthreads();

    floatx4 acc[2][2];
#pragma unroll
    for (int i = 0; i < 2; ++i)
#pragma unroll
        for (int j = 0; j < 2; ++j) acc[i][j] = (floatx4){0.f, 0.f, 0.f, 0.f};

    const int w    = t >> 6;
    const int lane = t & 63;
    const int quad = lane >> 4;
    const int lm   = lane & 15;
    const int aoff = ((w >> 1) * 32 + lm) * ASTR + quad * 8;
    const int boff = ((w & 1) * 32 + lm) * ASTR + quad * 8;

    int p = 0;
    for (int k0 = ks; k0 < ke; k0 += 32) {
        const bool more = (k0 + 32 < ke);
        if (more) {
            stage(p ^ 1);                       // consumes loads issued 1 iter ago
            if (k0 + 64 < ke) prefetch(k0 + 64); // issue 2 iters ahead
        }
        short8 a0 = *(const short8*)&As[p][aoff];
        short8 a1 = *(const short8*)&As[p][aoff + 16 * ASTR];
        short8 b0 = *(const short8*)&Ws[p][boff];
        short8 b1 = *(const short8*)&Ws[p][boff + 16 * ASTR];
        acc[0][0] = __builtin_amdgcn_mfma_f32_16x16x32_bf16(a0, b0, acc[0][0], 0, 0, 0);
        acc[0][1] = __builtin_amdgcn_mfma_f32_16x16x32_bf16(a0, b1, acc[0][1], 0, 0, 0);
        acc[1][0] = __builtin_amdgcn_mfma_f32_16x16x32_bf16(a1, b0, acc[1][0], 0, 0, 0);
        acc[1][1] = __builtin_amdgcn_mfma_f32_16x16x32_bf16(a1, b1, acc[1][1], 0, 0, 0);
        if (more) {
            __syncthreads();
            p ^= 1;
        }
    }

    const int rbase = m0 + (w >> 1) * 32 + quad * 4;
    const int cbase = n0 + (w & 1) * 32 + lm;
#pragma unroll
    for (int mt = 0; mt < 2; ++mt)
#pragma unroll
        for (int nt = 0; nt < 2; ++nt) {
            const int gc = cbase + nt * 16;
            if (NG && gc >= N) continue;
#pragma unroll
            for (int r = 0; r < 4; ++r) {
                const size_t gr = rbase + mt * 16 + r;
                float v = acc[mt][nt][r];
                if (ATOMIC) {
                    if (EPI == 1 && blockIdx.z == 0) v += bias[gc];
                    atomicAdd(&C[gr * ldc + gc], v);
                } else {
                    if (EPI == 1) v += bias[gc];
                    if (EPI == 2) v = softplus_f(v + bias[gc]);
                    C[gr * ldc + gc] = v;
                }
            }
        }
}

// ---------------------------------------------------------------------------
// Depthwise causal conv (width 4) + bias + SiLU; writes u (f32) and u_bf.
// ---------------------------------------------------------------------------
__global__ __launch_bounds__(256) void conv_silu_k(
    const float* __restrict__ xz, const float* __restrict__ w,
    const float* __restrict__ cb, float* __restrict__ u, short* __restrict__ ubf)
{
    int idx = blockIdx.x * 256 + threadIdx.x;
    if (idx >= MROWS * (D_INNER / 4)) return;
    int dq = idx % (D_INNER / 4);
    int m  = idx / (D_INNER / 4);
    int d0 = dq * 4;
    int b = m / L_, l = m % L_;
    float4 wq[4];
#pragma unroll
    for (int j = 0; j < 4; ++j) wq[j] = *(const float4*)(w + (d0 + j) * D_CONV);
    float acc[4];
#pragma unroll
    for (int j = 0; j < 4; ++j) acc[j] = cb[d0 + j];
#pragma unroll
    for (int tt = 0; tt < 4; ++tt) {
        int ll = l - 3 + tt;
        if (ll >= 0) {
            float4 xv = *(const float4*)(xz + (size_t)(b * L_ + ll) * (2 * D_INNER) + d0);
            acc[0] = fmaf(xv.x, ((const float*)&wq[0])[tt], acc[0]);
            acc[1] = fmaf(xv.y, ((const float*)&wq[1])[tt], acc[1]);
            acc[2] = fmaf(xv.z, ((const float*)&wq[2])[tt], acc[2]);
            acc[3] = fmaf(xv.w, ((const float*)&wq[3])[tt], acc[3]);
        }
    }
    float4 o = make_float4(silu_f(acc[0]), silu_f(acc[1]), silu_f(acc[2]), silu_f(acc[3]));
    *(float4*)(u + (size_t)m * D_INNER + d0) = o;
    uint2 pk;
    pk.x = pack2bf(o.x, o.y);
    pk.y = pack2bf(o.z, o.w);
    *(uint2*)(ubf + (size_t)m * D_INNER + d0) = pk;
}

// ---------------------------------------------------------------------------
// Fused selective scan, r6 refinements on the r5 carry-folded two-pass:
//  - phase 0 row-task dt-proj: each thread owns ONE row, computes BOTH
//    channels (r5: each row's xdbl was loaded twice; dtW was per-lane vector
//    loads although d0 is block-uniform -> now SGPR loads).
//  - {delta,u} packed as float2 in LDS -> one ds_read_b64/j instead of two
//    b32 in both passes.
//  - carry fold fixed-unrolled over NCH-1 with cndmask identity -> the 15
//    sPH loads batch into one lgkm wait (r5: runtime trip count serialized
//    15 dependent ~130cy load+fma steps).
//  - {P,H} packed as float2 (one b64 write/read).
// ---------------------------------------------------------------------------
__global__ __launch_bounds__(512, 4) void scan_fused_k(
    const float* __restrict__ xdbl, const float* __restrict__ u,
    const float* __restrict__ xz,
    const float* __restrict__ dtW, const float* __restrict__ dtb,
    const float* __restrict__ A_log, const float* __restrict__ Dp,
    short* __restrict__ ybf)
{
    __shared__ __align__(16) float2 sdu[NCH][SCH][DG];     // {delta,u} 8KB
    __shared__ __align__(16) float  sy[NCH][SCH][DG];      // 4KB
    __shared__ __align__(16) float2 sPH[NCH][DG][16];      // {P,H} 4KB

    const int t  = threadIdx.x;
    const int w  = t >> 6;          // wave 0..7
    const int l  = t & 63;
    const int ch = l >> 5;          // 0..1 -> which of the wave's two chunks
    const int c  = w * 2 + ch;      // chunk 0..15
    const int dl = (l >> 4) & 1;    // channel within block
    const int n  = l & 15;          // state index
    // XCD-chunked swizzle (bijective, 384 = 8 * 48): adjacent d-groups share
    // cache lines of u/xz/ybf -> keep them on one XCD (r1: FETCH 51->8MB).
    const int bx  = blockIdx.x;
    const int dgi = (bx & 7) * (D_INNER / DG / 8) + (bx >> 3);
    const int d0 = dgi * DG;
    const int d  = d0 + dl;
    const int b  = blockIdx.y;

    // row-task mapping (each thread owns one global row)
    const int tc = t >> 5, tj = t & 31;          // tc in {2w, 2w+1} -> wave-private
    const size_t trow = (size_t)b * L_ + t;

    // ---- phase 0: wave-private staging ----
    // early-issue phase-C gate load (consumed ~3000cy later)
    float2 rv  = *(const float2*)(xz + trow * (2 * D_INNER) + D_INNER + d0);
    float2 uv2 = *(const float2*)(u + trow * D_INNER + d0);

    // delta for BOTH channels of this thread's row; dtW/dtb are block-uniform
    {
        const float* wd = dtW + (size_t)d0 * DT_RANK;
        const float* xr = xdbl + trow * XPROJ_N;
        float acc0 = dtb[d0];
        float acc1 = dtb[d0 + 1];
#pragma unroll
        for (int q = 0; q < 6; ++q) {
            float4 xv = *(const float4*)(xr + q * 4);
            float4 w0 = *(const float4*)(wd + q * 4);
            float4 w1 = *(const float4*)(wd + DT_RANK + q * 4);
            acc0 = fmaf(xv.x, w0.x, acc0); acc0 = fmaf(xv.y, w0.y, acc0);
            acc0 = fmaf(xv.z, w0.z, acc0); acc0 = fmaf(xv.w, w0.w, acc0);
            acc1 = fmaf(xv.x, w1.x, acc1); acc1 = fmaf(xv.y, w1.y, acc1);
            acc1 = fmaf(xv.z, w1.z, acc1); acc1 = fmaf(xv.w, w1.w, acc1);
        }
        float4 pk = make_float4(softplus_f(acc0), uv2.x, softplus_f(acc1), uv2.y);
        *(float4*)&sdu[tc][tj][0] = pk;   // one ds_write_b128
    }
    wave_lds_fence();   // sdu for chunks {2w,2w+1} produced+consumed by wave w

    const float Av = -expf(A_log[d * N_STATE + n]);
    const float Dd = Dp[d];
    const float* xbn = xdbl + ((size_t)b * L_ + c * SCH) * XPROJ_N + DT_RANK + n;

    // ---- pass 1: chunk-local end-state H and decay product P (no reduce) ----
    {
        float h = 0.f, sdv = 0.f;
        float rB[8];
#pragma unroll
        for (int q = 0; q < 8; ++q) rB[q] = xbn[q * XPROJ_N];
#pragma unroll
        for (int g = 0; g < SCH / 8; ++g) {
            float nB[8];
            if (g + 1 < SCH / 8) {
#pragma unroll
                for (int q = 0; q < 8; ++q) nB[q] = xbn[(g * 8 + 8 + q) * XPROJ_N];
            }
#pragma unroll
            for (int q = 0; q < 8; ++q) {
                const int j = g * 8 + q;
                float2 du = *(const float2*)&sdu[c][j][dl];
                float e  = __expf(du.x * Av);
                h = fmaf(e, h, du.x * du.y * rB[q]);
                sdv += du.x;
            }
#pragma unroll
            for (int q = 0; q < 8; ++q) rB[q] = nB[q];
        }
        float2 ph;
        ph.x = __expf(sdv * Av);   // prod of exps = exp of sum
        ph.y = h;
        *(float2*)&sPH[c][dl][n] = ph;
    }

    // issue pass-2 group-0 B/C loads BEFORE the barrier (latency cover)
    float rB[8], rC[8];
#pragma unroll
    for (int q = 0; q < 8; ++q) {
        rB[q] = xbn[q * XPROJ_N];
        rC[q] = xbn[q * XPROJ_N + N_STATE];
    }
    __syncthreads();    // the only cross-wave exchange (sPH)

    // ---- carry-in: fixed-unroll masked fold (all 15 loads batch) ----
    float hs = 0.f;
#pragma unroll
    for (int s = 0; s < NCH - 1; ++s) {
        float2 ph = *(const float2*)&sPH[s][dl][n];
        const bool m = s < c;
        hs = fmaf(m ? ph.x : 1.f, hs, m ? ph.y : 0.f);
    }

    // ---- pass 2: full recurrence from h=hs; y is final directly ----
    {
        float h = hs;
#pragma unroll
        for (int g = 0; g < SCH / 8; ++g) {
            float nB[8], nC[8];
            if (g + 1 < SCH / 8) {
#pragma unroll
                for (int q = 0; q < 8; ++q) {
                    nB[q] = xbn[(g * 8 + 8 + q) * XPROJ_N];
                    nC[q] = xbn[(g * 8 + 8 + q) * XPROJ_N + N_STATE];
                }
            }
#pragma unroll
            for (int q = 0; q < 8; ++q) {
                const int j = g * 8 + q;
                float2 du = *(const float2*)&sdu[c][j][dl];
                float e  = __expf(du.x * Av);
                h = fmaf(e, h, du.x * du.y * rB[q]);
                float p = h * rC[q];
                p = dpp_radd<0x128>(p);
                p = dpp_radd<0x124>(p);
                p = dpp_radd<0x122>(p);
                p = dpp_radd<0x121>(p);
                if (n == 0) sy[c][j][dl] = fmaf(du.y, Dd, p);
            }
#pragma unroll
            for (int q = 0; q < 8; ++q) { rB[q] = nB[q]; rC[q] = nC[q]; }
        }
    }
    wave_lds_fence();   // sy for chunks {2w,2w+1} is wave-private

    // ---- phase C: gate with silu(res) and emit bf16 ----
    {
        float2 yv = *(const float2*)&sy[tc][tj][0];
        float o0 = yv.x * silu_f(rv.x);
        float o1 = yv.y * silu_f(rv.y);
        *(unsigned*)(ybf + trow * D_INNER + d0) = pack2bf(o0, o1);
    }
}

// ---------------------------------------------------------------------------
extern "C" void kernel_launch(void* const* d_in, const int* in_sizes, int n_in,
                              void* d_out, int out_size, void* d_ws, size_t ws_size,
                              hipStream_t stream)
{
    const float* input_ids = (const float*)d_in[0];
    const float* fc_W      = (const float*)d_in[1];
    const float* fc_b      = (const float*)d_in[2];
    const float* in_proj_W = (const float*)d_in[3];
    const float* conv_W    = (const float*)d_in[4];
    const float* conv_b    = (const float*)d_in[5];
    const float* x_proj_W  = (const float*)d_in[6];
    const float* dt_proj_W = (const float*)d_in[7];
    const float* dt_proj_b = (const float*)d_in[8];
    const float* A_log     = (const float*)d_in[9];
    const float* Dp        = (const float*)d_in[10];
    const float* out_proj_W= (const float*)d_in[11];
    const float* norm_W    = (const float*)d_in[12];
    const float* normf_W   = (const float*)d_in[13];
    const float* head_W    = (const float*)d_in[14];
    float* out = (float*)d_out;

    float* ws       = (float*)d_ws;
    // f32 region: x_ws + per-layer xdbl contiguous (single zero span), then xz, u.
    float* x_ws     = ws;                                        // M*384
    float* xdbl_ws  = x_ws    + (size_t)MROWS * D_MODEL;         // 4 * M*56
    float* xz_ws    = xdbl_ws + (size_t)N_LAYER * MROWS * XPROJ_N; // M*1536
    float* u_ws     = xz_ws   + (size_t)MROWS * 2 * D_INNER;     // M*768
    // bf16 region
    short* bf       = (short*)(u_ws + (size_t)MROWS * D_INNER);
    short* wbf_fc   = bf;
    short* wbf_in   = wbf_fc  + (size_t)D_MODEL * VOCAB;
    short* wbf_x    = wbf_in  + (size_t)N_LAYER * 2 * D_INNER * D_MODEL;
    short* wbf_out  = wbf_x   + (size_t)N_LAYER * XPROJ_N * D_INNER;
    short* wbf_head = wbf_out + (size_t)N_LAYER * D_MODEL * D_INNER;
    short* ids_bf   = wbf_head+ (size_t)FEAT * D_MODEL;
    short* ubf_ws   = ids_bf  + (size_t)MROWS * VOCAB;
    short* ybf_ws   = ubf_ws  + (size_t)MROWS * D_INNER;
    short* xnorm_bf = ybf_ws  + (size_t)MROWS * D_INNER;         // M*384 bf16

    const dim3 blk(256);
    const dim3 blk512(512);

    // --- one-shot cast to bf16 (weights + input_ids) + zero atomic dst buffers ---
    CastDesc cd;
    cd.src[0] = fc_W;       cd.dst[0] = wbf_fc;
    cd.src[1] = in_proj_W;  cd.dst[1] = wbf_in;
    cd.src[2] = x_proj_W;   cd.dst[2] = wbf_x;
    cd.src[3] = out_proj_W; cd.dst[3] = wbf_out;
    cd.src[4] = head_W;     cd.dst[4] = wbf_head;
    cd.src[5] = input_ids;  cd.dst[5] = ids_bf;
    unsigned c0 = (unsigned)(D_MODEL * VOCAB / 4);
    unsigned c1 = c0 + (unsigned)(N_LAYER * 2 * D_INNER * D_MODEL / 4);
    unsigned c2 = c1 + (unsigned)(N_LAYER * XPROJ_N * D_INNER / 4);
    unsigned c3 = c2 + (unsigned)(N_LAYER * D_MODEL * D_INNER / 4);
    unsigned c4 = c3 + (unsigned)(FEAT * D_MODEL / 4);
    unsigned c5 = c4 + (unsigned)(MROWS * VOCAB / 4);
    cd.cum[0] = c0; cd.cum[1] = c1; cd.cum[2] = c2;
    cd.cum[3] = c3; cd.cum[4] = c4; cd.cum[5] = c5;
    const unsigned zero4 = (unsigned)((MROWS * D_MODEL + N_LAYER * MROWS * XPROJ_N) / 4);
    cast_w_k<<<(c5 + zero4 + 255) / 256, blk, 0, stream>>>(cd, c5, (float4*)x_ws, zero4);

    // x = input_ids @ fc_W.T + fc_b   (A pre-cast bf16, split-K=7, atomic)
    mfma_gemm<1, true, false, true><<<dim3(D_MODEL / 64, MROWS / 64, 7), blk, 0, stream>>>(
        nullptr, ids_bf, wbf_fc, fc_b, x_ws,
        MROWS, D_MODEL, VOCAB, VOCAB, D_MODEL, 256);

    for (int i = 0; i < N_LAYER; ++i) {
        float* xdbl_i = xdbl_ws + (size_t)i * MROWS * XPROJ_N;

        // xnorm = rmsnorm(x, norm_W) -> bf16 (one pass)
        rmsnorm_cast_k<<<MROWS * 8 / 256, blk, 0, stream>>>(
            x_ws, norm_W + i * D_MODEL, (unsigned*)xnorm_bf);

        // xz = xnorm @ in_proj_W.T  (pure ABF GEMM)
        mfma_gemm<0, false, false, true><<<dim3(2 * D_INNER / 64, MROWS / 64, 1), blk, 0, stream>>>(
            nullptr, xnorm_bf, wbf_in + (size_t)i * 2 * D_INNER * D_MODEL,
            nullptr, xz_ws,
            MROWS, 2 * D_INNER, D_MODEL, D_MODEL, 2 * D_INNER, D_MODEL);

        // u = silu(conv(xz[:, :768]) + conv_b)  (f32 + bf16 copies)
        conv_silu_k<<<(MROWS * (D_INNER / 4) + 255) / 256, blk, 0, stream>>>(
            xz_ws, conv_W + (size_t)i * D_INNER * D_CONV, conv_b + i * D_INNER,
            u_ws, ubf_ws);

        // x_dbl = u @ x_proj_W[i].T  (A pre-cast bf16, N=56 guarded, split-K=6,
        // dst pre-zeroed once in cast_w_k -- per-layer buffer)
        mfma_gemm<0, true, true, true><<<dim3(1, MROWS / 64, 6), blk, 0, stream>>>(
            nullptr, ubf_ws, wbf_x + (size_t)i * XPROJ_N * D_INNER,
            nullptr, xdbl_i,
            MROWS, XPROJ_N, D_INNER, D_INNER, XPROJ_N, 128);

        // fused: dt_proj+softplus -> carry-folded two-pass scan -> gate -> ybf
        scan_fused_k<<<dim3(D_INNER / DG, B_), blk512, 0, stream>>>(
            xdbl_i, u_ws, xz_ws,
            dt_proj_W + (size_t)i * D_INNER * DT_RANK, dt_proj_b + i * D_INNER,
            A_log + (size_t)i * D_INNER * N_STATE, Dp + i * D_INNER, ybf_ws);

        // x += ybf @ out_proj_W.T  (A pre-cast bf16 gated y, split-K=2, atomic residual)
        mfma_gemm<0, true, false, true><<<dim3(D_MODEL / 64, MROWS / 64, 2), blk, 0, stream>>>(
            nullptr, ybf_ws, wbf_out + (size_t)i * D_MODEL * D_INNER,
            nullptr, x_ws,
            MROWS, D_MODEL, D_INNER, D_INNER, D_MODEL, 384);
    }

    // out = rmsnorm(x, normf_W) @ head_W.T  (rmsnorm pre-pass + ABF)
    rmsnorm_cast_k<<<MROWS * 8 / 256, blk, 0, stream>>>(
        x_ws, normf_W, (unsigned*)xnorm_bf);
    mfma_gemm<0, false, false, true><<<dim3(FEAT / 64, MROWS / 64, 1), blk, 0, stream>>>(
        nullptr, xnorm_bf, wbf_head, nullptr, out,
        MROWS, FEAT, D_MODEL, D_MODEL, FEAT, D_MODEL);
}